// Round 11
// baseline (4005.605 us; speedup 1.0000x reference)
//
#include <hip/hip_runtime.h>
#include <math.h>

#define T_LEN 76800
#define T_MEL 300
#define B_N 4

typedef __attribute__((ext_vector_type(8))) short bf16x8;
typedef __attribute__((ext_vector_type(4))) float f32x4;
typedef __attribute__((ext_vector_type(4))) unsigned short u16x4;

__device__ inline unsigned short f2bf(float x) {
    unsigned u = __float_as_uint(x);
    u += 0x7fffu + ((u >> 16) & 1u);
    return (unsigned short)(u >> 16);
}
__device__ inline float bf2f(unsigned short h) {
    return __uint_as_float(((unsigned)h) << 16);
}

// ---------------- prep kernels ----------------

__global__ void cu0_kernel(const float* __restrict__ c, const float* __restrict__ up_in_w,
                           float* __restrict__ cu0) {
    int idx = blockIdx.x * 256 + threadIdx.x;
    if (idx >= B_N * 80 * T_MEL) return;
    int m = idx % T_MEL; int rest = idx / T_MEL; int o = rest % 80; int b = rest / 80;
    const float* crow = c + (size_t)(b * 80) * T_MEL;
    const float* wrow = up_in_w + o * 80;
    float acc = 0.f;
    for (int i = 0; i < 80; ++i) acc = fmaf(wrow[i], crow[(size_t)i * T_MEL + m], acc);
    cu0[idx] = acc;
}

// composite 33-tap filter prefix sums + exact edge vectors (r1 derivation, validated)
__global__ void filt_kernel(const float* __restrict__ up_conv_w, float* __restrict__ filt) {
    if (threadIdx.x != 0 || blockIdx.x != 0) return;
    float F[33], tmp[33];
    for (int j = 0; j < 9; ++j) F[j] = up_conv_w[j];
    int len = 9;
    for (int s = 1; s < 4; ++s) {
        const float* w = up_conv_w + s * 9;
        int nl = len + 8;
        for (int j = 0; j < nl; ++j) {
            float acc = 0.f;
            for (int a = 0; a < 9; ++a) { int bi = j - a; if (bi >= 0 && bi < len) acc += w[a] * F[bi]; }
            tmp[j] = acc;
        }
        for (int j = 0; j < nl; ++j) F[j] = tmp[j];
        len = nl;
    }
    float run = 0.f;
    for (int n = 0; n < 33; ++n) { filt[n] = run; run += F[n]; }
    filt[33] = run; filt[34] = run;
    const float* w1 = up_conv_w + 0;  const float* w2 = up_conv_w + 9;
    const float* w3 = up_conv_w + 18; const float* w4 = up_conv_w + 27;
    {
        float y1[28], y2[24], y3[20];
        for (int u = 0; u < 28; ++u) { float a = 0; for (int k = 0; k < 9; ++k) { int v = u + k - 4; if (v >= 0) a += w1[k]; } y1[u] = a; }
        for (int u = 0; u < 24; ++u) { float a = 0; for (int k = 0; k < 9; ++k) { int v = u + k - 4; if (v >= 0) a += w2[k] * y1[v]; } y2[u] = a; }
        for (int u = 0; u < 20; ++u) { float a = 0; for (int k = 0; k < 9; ++k) { int v = u + k - 4; if (v >= 0) a += w3[k] * y2[v]; } y3[u] = a; }
        for (int t = 0; t < 16; ++t) { float a = 0; for (int k = 0; k < 9; ++k) { int v = t + k - 4; if (v >= 0) a += w4[k] * y3[v]; } filt[40 + t] = a; }
    }
    {
        float z1[44], z2[44], z3[44];
        for (int u = 0; u < 44; ++u) { float a = 0; for (int k = 0; k < 9; ++k) { int v = u + k - 4; if (v <= 43) a += w1[k]; } z1[u] = a; }
        for (int u = 0; u < 44; ++u) { float a = 0; for (int k = 0; k < 9; ++k) { int v = u + k - 4; if (v <= 43) a += w2[k] * z1[v < 0 ? 0 : v]; } z2[u] = a; }
        for (int u = 0; u < 44; ++u) { float a = 0; for (int k = 0; k < 9; ++k) { int v = u + k - 4; if (v <= 43) a += w3[k] * z2[v < 0 ? 0 : v]; } z3[u] = a; }
        for (int j = 0; j < 16; ++j) {
            int u = 28 + j; float a = 0;
            for (int k = 0; k < 9; ++k) { int v = u + k - 4; if (v <= 43) a += w4[k] * z3[v < 0 ? 0 : v]; }
            filt[56 + j] = a;
        }
    }
}

__global__ void g_kernel(const float* __restrict__ cu0, const float* __restrict__ aux_w,
                         float* __restrict__ g) {
    int idx = blockIdx.x * 256 + threadIdx.x;
    if (idx >= 30 * B_N * 128 * T_MEL) return;
    int m = idx % T_MEL; int rest = idx / T_MEL; int o = rest % 128; rest /= 128;
    int b = rest % B_N; int i = rest / B_N;
    const float* wrow = aux_w + ((size_t)i * 128 + o) * 80;
    const float* crow = cu0 + (size_t)(b * 80) * T_MEL + m;
    float acc = 0.f;
    for (int cc = 0; cc < 80; ++cc) acc = fmaf(wrow[cc], crow[(size_t)cc * T_MEL], acc);
    g[idx] = acc;
}

// x0 in [b][t][ch] bf16 layout (single plane)
__global__ void first_kernel(const float* __restrict__ noise, const float* __restrict__ fw,
                             const float* __restrict__ fb,
                             unsigned short* __restrict__ xh) {
    int idx = blockIdx.x * 256 + threadIdx.x;
    if (idx >= B_N * T_LEN * 64) return;
    int i = idx & 63; int rest = idx >> 6; int t = rest % T_LEN; int b = rest / T_LEN;
    float v = fmaf(fw[i], noise[(size_t)b * T_LEN + t], fb[i]);
    xh[idx] = f2bf(v);
}

// conv weights -> MFMA A-fragment order, hi/lo planes.
// idx = (((layer*3+tap)*2+ch)*8+m)*64+lane ; elem j: o=m*16+(l&15), i=ch*32+(l>>4)*8+j
__global__ void wfrag_kernel(const float* __restrict__ conv_w,
                             unsigned short* __restrict__ wfh, unsigned short* __restrict__ wfl) {
    int idx = blockIdx.x * 256 + threadIdx.x;
    if (idx >= 30 * 3 * 2 * 8 * 64) return;
    int l = idx & 63; int r = idx >> 6;
    int m = r & 7; r >>= 3;
    int ch = r & 1; r >>= 1;
    int tap = r % 3; int layer = r / 3;
    int o = m * 16 + (l & 15);
    int i0 = ch * 32 + (l >> 4) * 8;
    #pragma unroll
    for (int j = 0; j < 8; ++j) {
        float v = conv_w[(((size_t)layer * 128 + o) * 64 + i0 + j) * 3 + tap];
        unsigned short h = f2bf(v);
        wfh[(size_t)idx * 8 + j] = h;
        wfl[(size_t)idx * 8 + j] = f2bf(v - bf2f(h));
    }
}

// skip/out weights -> fragment order. idx = ((layer*2+ch)*8+m)*64+lane
__global__ void w2frag_kernel(const float* __restrict__ skip_w, const float* __restrict__ out_w,
                              unsigned short* __restrict__ w2h, unsigned short* __restrict__ w2l) {
    int idx = blockIdx.x * 256 + threadIdx.x;
    if (idx >= 30 * 2 * 8 * 64) return;
    int l = idx & 63; int r = idx >> 6;
    int m = r & 7; r >>= 3;
    int ch = r & 1; int layer = r >> 1;
    int o = m * 16 + (l & 15);
    int z0 = ch * 32 + (l >> 4) * 8;
    #pragma unroll
    for (int j = 0; j < 8; ++j) {
        float v = (o < 64) ? skip_w[((size_t)layer * 64 + o) * 64 + z0 + j]
                           : out_w[((size_t)layer * 64 + (o - 64)) * 64 + z0 + j];
        unsigned short h = f2bf(v);
        w2h[(size_t)idx * 8 + j] = h;
        w2l[(size_t)idx * 8 + j] = f2bf(v - bf2f(h));
    }
}

// ---------------- main residual block (r9 body; phase-2 split to halve reg peak) ---
// 256 thr = 4 waves; tile 128 o x 128 t; wave wv owns t in [wv*32, wv*32+32) (nt=0,1).
// Phase1: 6 stages (tap,ch); W frags LDS-staged (dbuf); x bf16 direct global; 2 MFMAs
// per fragment. Gate -> z split -> LDS (wave-private rows, XOR swizzle); acc dies.
// Phase2a: skip rows (m0-3, 32-reg acc) + skip epilogue; then Phase2b: out rows
// (m4-7) + x epilogue. launch_bounds(256,4) hard-caps 128 regs -> 4 waves/SIMD.
__global__ __launch_bounds__(256, 4) void block_kernel(
    const unsigned short* __restrict__ xin, unsigned short* __restrict__ xout,
    float* __restrict__ skip,   // [b][t][64]
    const float* __restrict__ g, const float* __restrict__ filt,
    const unsigned short* __restrict__ wfh, const unsigned short* __restrict__ wfl,
    const float* __restrict__ conv_b,
    const unsigned short* __restrict__ w2h, const unsigned short* __restrict__ w2l,
    const float* __restrict__ skip_b, const float* __restrict__ out_b,
    int d, int first)
{
    // phase1: two W bufs [hi 4096 | lo 4096] ushorts each; phase2: Z hi [0..8192), lo [8192..)
    __shared__ unsigned short U[16384];
    __shared__ float glm[128], gll[128], glr[128], bl1[128], bl2[128];

    const int tid = threadIdx.x;
    const int wv = tid >> 6, ln = tid & 63;
    const int g4 = ln >> 4, l15 = ln & 15;
    const int b = blockIdx.y;
    // XCD-chunked bijective swizzle (600 = 8*75)
    const int bx = (blockIdx.x & 7) * 75 + (blockIdx.x >> 3);
    const int t0 = bx * 128;
    const int m0 = t0 >> 8;

    if (tid < 128) {
        int o = tid;
        const float* gb = g + ((size_t)b * 128 + o) * T_MEL;
        int ml = m0 > 0 ? m0 - 1 : 0;
        int mr = m0 < 299 ? m0 + 1 : 299;
        glm[o] = gb[m0]; gll[o] = gb[ml]; glr[o] = gb[mr];
        bl1[o] = conv_b[o];
    } else {
        int o = tid - 128;
        bl2[o] = (o < 64) ? skip_b[o] : out_b[o - 64];
    }

    // prologue: stage W s=0 into buf 0
    {
        bf16x8 h0 = *(const bf16x8*)(wfh + tid * 16);
        bf16x8 h1 = *(const bf16x8*)(wfh + tid * 16 + 8);
        bf16x8 l0 = *(const bf16x8*)(wfl + tid * 16);
        bf16x8 l1 = *(const bf16x8*)(wfl + tid * 16 + 8);
        *(bf16x8*)&U[tid * 16] = h0;        *(bf16x8*)&U[tid * 16 + 8] = h1;
        *(bf16x8*)&U[4096 + tid * 16] = l0; *(bf16x8*)&U[4096 + tid * 16 + 8] = l1;
    }
    __syncthreads();

    // per-ntile aux interpolation coefficients (exact)
    float am[2], al[2], ar[2];
    const float K = filt[34];
    #pragma unroll
    for (int nt = 0; nt < 2; ++nt) {
        int t = t0 + wv * 32 + nt * 16 + l15;
        int r = t & 255;
        float Am = K, Al = 0.f, Ar = 0.f;
        if (t < 16)               { Am = filt[40 + t]; }
        else if (t >= T_LEN - 16) { Am = filt[56 + (t - (T_LEN - 16))]; }
        else if (r < 16)  { float blv = filt[16 - r];     Am = K - blv; Al = blv; }
        else if (r > 239) { float bh = K - filt[272 - r]; Am = K - bh;  Ar = bh; }
        am[nt] = Am; al[nt] = Al; ar[nt] = Ar;
    }

    f32x4 acc[8][2];
    #pragma unroll
    for (int m = 0; m < 8; ++m)
        #pragma unroll
        for (int nt = 0; nt < 2; ++nt)
            #pragma unroll
            for (int r = 0; r < 4; ++r) {
                int o = m * 16 + 4 * g4 + r;
                acc[m][nt][r] = bl1[o] + am[nt] * glm[o] + al[nt] * gll[o] + ar[nt] * glr[o];
            }

    bf16x8 zfrag;
    #pragma unroll
    for (int j = 0; j < 8; ++j) zfrag[j] = 0;

    const size_t xbase = (size_t)b * T_LEN * 64;

    // ---- phase 1: 6 stages (tap,ch), W from LDS (dbuf), x (bf16) from global ----
    #pragma unroll
    for (int s = 0; s < 6; ++s) {
        const int cur = s & 1;
        if (s < 5) {  // stage next into the other buffer
            const size_t gb_ = (size_t)(s + 1) * 4096 + tid * 16;
            bf16x8 h0 = *(const bf16x8*)(wfh + gb_);
            bf16x8 h1 = *(const bf16x8*)(wfh + gb_ + 8);
            bf16x8 l0 = *(const bf16x8*)(wfl + gb_);
            bf16x8 l1 = *(const bf16x8*)(wfl + gb_ + 8);
            unsigned short* dst = U + (cur ^ 1) * 8192;
            *(bf16x8*)&dst[tid * 16] = h0;        *(bf16x8*)&dst[tid * 16 + 8] = h1;
            *(bf16x8*)&dst[4096 + tid * 16] = l0; *(bf16x8*)&dst[4096 + tid * 16 + 8] = l1;
        }
        const int tap = s >> 1, ch = s & 1;
        const int shift = (tap - 1) * d;
        bf16x8 bx[2];
        #pragma unroll
        for (int nt = 0; nt < 2; ++nt) {
            int te = t0 + wv * 32 + nt * 16 + l15 + shift;
            if ((unsigned)te < (unsigned)T_LEN) {
                size_t a = xbase + (size_t)te * 64 + ch * 32 + g4 * 8;
                bx[nt] = *(const bf16x8*)(xin + a);
            } else {
                bx[nt] = zfrag;
            }
        }
        const unsigned short* Wh = U + cur * 8192;
        #pragma unroll
        for (int m = 0; m < 8; ++m) {
            const bf16x8 ah  = *(const bf16x8*)&Wh[(m * 64 + ln) * 8];
            const bf16x8 alo = *(const bf16x8*)&Wh[4096 + (m * 64 + ln) * 8];
            #pragma unroll
            for (int nt = 0; nt < 2; ++nt) {
                acc[m][nt] = __builtin_amdgcn_mfma_f32_16x16x32_bf16(ah,  bx[nt], acc[m][nt], 0, 0, 0);
                acc[m][nt] = __builtin_amdgcn_mfma_f32_16x16x32_bf16(alo, bx[nt], acc[m][nt], 0, 0, 0);
            }
        }
        __syncthreads();
    }

    // ---- gate -> FULL z (split) -> LDS, XOR-swizzled; acc dies here ----
    #pragma unroll
    for (int zm = 0; zm < 4; ++zm)
        #pragma unroll
        for (int nt = 0; nt < 2; ++nt) {
            u16x4 zh4, zl4;
            #pragma unroll
            for (int r = 0; r < 4; ++r) {
                float a_ = acc[zm][nt][r], b_ = acc[zm + 4][nt][r];
                float z = tanhf(a_) * (1.f / (1.f + expf(-b_)));
                unsigned short h = f2bf(z);
                zh4[r] = h; zl4[r] = f2bf(z - bf2f(h));
            }
            int trow = wv * 32 + nt * 16 + l15;
            int col = (zm * 16 + 4 * g4) ^ ((l15 & 7) << 3);
            *(u16x4*)&U[trow * 64 + col] = zh4;
            *(u16x4*)&U[8192 + trow * 64 + col] = zl4;
        }
    // Z rows are wave-private -> no barrier.

    const size_t sbase = (size_t)b * T_LEN * 64;

    // ---- phase 2a: skip rows (m = 0..3) ----
    {
        f32x4 acc2[4][2];
        #pragma unroll
        for (int m = 0; m < 4; ++m)
            #pragma unroll
            for (int nt = 0; nt < 2; ++nt)
                #pragma unroll
                for (int r = 0; r < 4; ++r)
                    acc2[m][nt][r] = bl2[m * 16 + 4 * g4 + r];

        #pragma unroll
        for (int chh = 0; chh < 2; ++chh) {
            bf16x8 bzh[2], bzl[2];
            #pragma unroll
            for (int nt = 0; nt < 2; ++nt) {
                int trow = wv * 32 + nt * 16 + l15;
                int chunk = (chh * 4 + g4) ^ (l15 & 7);
                bzh[nt] = *(const bf16x8*)&U[trow * 64 + chunk * 8];
                bzl[nt] = *(const bf16x8*)&U[8192 + trow * 64 + chunk * 8];
            }
            #pragma unroll
            for (int m = 0; m < 4; ++m) {
                const bf16x8 ah  = *(const bf16x8*)(w2h + ((size_t)((chh * 8 + m) * 64 + ln)) * 8);
                const bf16x8 alo = *(const bf16x8*)(w2l + ((size_t)((chh * 8 + m) * 64 + ln)) * 8);
                #pragma unroll
                for (int nt = 0; nt < 2; ++nt) {
                    acc2[m][nt] = __builtin_amdgcn_mfma_f32_16x16x32_bf16(ah,  bzh[nt], acc2[m][nt], 0, 0, 0);
                    acc2[m][nt] = __builtin_amdgcn_mfma_f32_16x16x32_bf16(ah,  bzl[nt], acc2[m][nt], 0, 0, 0);
                    acc2[m][nt] = __builtin_amdgcn_mfma_f32_16x16x32_bf16(alo, bzh[nt], acc2[m][nt], 0, 0, 0);
                }
            }
        }
        // skip epilogue (acc2 dies here)
        #pragma unroll
        for (int m = 0; m < 4; ++m)
            #pragma unroll
            for (int nt = 0; nt < 2; ++nt) {
                int t = t0 + wv * 32 + nt * 16 + l15;
                int o0 = m * 16 + 4 * g4;
                float* sp = skip + sbase + (size_t)t * 64 + o0;
                float4 v = make_float4(acc2[m][nt][0], acc2[m][nt][1], acc2[m][nt][2], acc2[m][nt][3]);
                if (!first) {
                    float4 o = *(const float4*)sp;
                    v.x += o.x; v.y += o.y; v.z += o.z; v.w += o.w;
                }
                *(float4*)sp = v;
            }
    }

    // ---- phase 2b: out rows (m = 4..7), residual x epilogue ----
    {
        f32x4 acc3[4][2];
        #pragma unroll
        for (int m = 0; m < 4; ++m)
            #pragma unroll
            for (int nt = 0; nt < 2; ++nt)
                #pragma unroll
                for (int r = 0; r < 4; ++r)
                    acc3[m][nt][r] = bl2[(m + 4) * 16 + 4 * g4 + r];

        #pragma unroll
        for (int chh = 0; chh < 2; ++chh) {
            bf16x8 bzh[2], bzl[2];
            #pragma unroll
            for (int nt = 0; nt < 2; ++nt) {
                int trow = wv * 32 + nt * 16 + l15;
                int chunk = (chh * 4 + g4) ^ (l15 & 7);
                bzh[nt] = *(const bf16x8*)&U[trow * 64 + chunk * 8];
                bzl[nt] = *(const bf16x8*)&U[8192 + trow * 64 + chunk * 8];
            }
            #pragma unroll
            for (int m = 0; m < 4; ++m) {
                const bf16x8 ah  = *(const bf16x8*)(w2h + ((size_t)((chh * 8 + m + 4) * 64 + ln)) * 8);
                const bf16x8 alo = *(const bf16x8*)(w2l + ((size_t)((chh * 8 + m + 4) * 64 + ln)) * 8);
                #pragma unroll
                for (int nt = 0; nt < 2; ++nt) {
                    acc3[m][nt] = __builtin_amdgcn_mfma_f32_16x16x32_bf16(ah,  bzh[nt], acc3[m][nt], 0, 0, 0);
                    acc3[m][nt] = __builtin_amdgcn_mfma_f32_16x16x32_bf16(ah,  bzl[nt], acc3[m][nt], 0, 0, 0);
                    acc3[m][nt] = __builtin_amdgcn_mfma_f32_16x16x32_bf16(alo, bzh[nt], acc3[m][nt], 0, 0, 0);
                }
            }
        }
        #pragma unroll
        for (int m = 0; m < 4; ++m)
            #pragma unroll
            for (int nt = 0; nt < 2; ++nt) {
                int t = t0 + wv * 32 + nt * 16 + l15;
                int o0 = m * 16 + 4 * g4;
                size_t a = xbase + (size_t)t * 64 + o0;
                u16x4 xh4 = *(const u16x4*)(xin + a);
                u16x4 oh;
                #pragma unroll
                for (int r = 0; r < 4; ++r) {
                    float xi = bf2f(xh4[r]);
                    float v = (acc3[m][nt][r] + xi) * 0.25f;
                    oh[r] = f2bf(v);
                }
                *(u16x4*)(xout + a) = oh;
            }
    }
}

// ---------------- epilogue ----------------
__global__ void final_kernel(const float* __restrict__ skip,
                             const float* __restrict__ l1w, const float* __restrict__ l1b,
                             const float* __restrict__ l2w, const float* __restrict__ l2b,
                             float* __restrict__ out) {
    int idx = blockIdx.x * 256 + threadIdx.x;
    if (idx >= B_N * T_LEN) return;
    int t = idx % T_LEN; int b = idx / T_LEN;
    const float scale = 0.18257418583505536f; // sqrt(1/30)
    float rbuf[64];
    const float* srow = skip + ((size_t)b * T_LEN + t) * 64;
    #pragma unroll
    for (int s = 0; s < 64; ++s) {
        float v = srow[s] * scale;
        rbuf[s] = v > 0.f ? v : 0.f;
    }
    float oacc = l2b[0];
    for (int cch = 0; cch < 64; ++cch) {
        float a = l1b[cch];
        const float* wrow = l1w + (size_t)cch * 64;
        #pragma unroll
        for (int s = 0; s < 64; ++s) a = fmaf(wrow[s], rbuf[s], a);
        a = a > 0.f ? a : 0.f;
        oacc = fmaf(l2w[cch], a, oacc);
    }
    out[idx] = oacc;
}

// ---------------- launch ----------------
extern "C" void kernel_launch(void* const* d_in, const int* in_sizes, int n_in,
                              void* d_out, int out_size, void* d_ws, size_t ws_size,
                              hipStream_t stream) {
    const float* c          = (const float*)d_in[0];
    const float* noise      = (const float*)d_in[1];
    const float* first_w    = (const float*)d_in[2];
    const float* first_b    = (const float*)d_in[3];
    const float* up_in_w    = (const float*)d_in[4];
    const float* up_conv_w  = (const float*)d_in[5];
    const float* blk_conv_w = (const float*)d_in[6];
    const float* blk_conv_b = (const float*)d_in[7];
    const float* blk_aux_w  = (const float*)d_in[8];
    const float* blk_out_w  = (const float*)d_in[9];
    const float* blk_out_b  = (const float*)d_in[10];
    const float* blk_skip_w = (const float*)d_in[11];
    const float* blk_skip_b = (const float*)d_in[12];
    const float* last1_w    = (const float*)d_in[13];
    const float* last1_b    = (const float*)d_in[14];
    const float* last2_w    = (const float*)d_in[15];
    const float* last2_b    = (const float*)d_in[16];
    float* out = (float*)d_out;
    float* ws  = (float*)d_ws;

    size_t off = 0;
    float* cu0  = ws + off; off += 96256;
    float* g    = ws + off; off += 30ull * 4 * 128 * T_MEL;   // 4,608,000
    float* filt = ws + off; off += 128;
    float* skip = ws + off; off += 4ull * 64 * T_LEN;         // [b][t][64]
    unsigned short* base16 = (unsigned short*)(ws + off);
    size_t o16 = 0;
    const size_t XPLANE = (size_t)B_N * T_LEN * 64;
    unsigned short* xA = base16 + o16; o16 += XPLANE;
    unsigned short* xB = base16 + o16; o16 += XPLANE;
    unsigned short* wfh = base16 + o16; o16 += 30ull * 24576;
    unsigned short* wfl = base16 + o16; o16 += 30ull * 24576;
    unsigned short* w2h = base16 + o16; o16 += 30ull * 8192;
    unsigned short* w2l = base16 + o16; o16 += 30ull * 8192;
    if (ws_size < off * sizeof(float) + o16 * sizeof(unsigned short)) return;

    hipLaunchKernelGGL(cu0_kernel, dim3((B_N * 80 * T_MEL + 255) / 256), dim3(256), 0, stream,
                       c, up_in_w, cu0);
    hipLaunchKernelGGL(filt_kernel, dim3(1), dim3(64), 0, stream, up_conv_w, filt);
    hipLaunchKernelGGL(g_kernel, dim3((30 * B_N * 128 * T_MEL + 255) / 256), dim3(256), 0, stream,
                       cu0, blk_aux_w, g);
    hipLaunchKernelGGL(first_kernel, dim3((B_N * T_LEN * 64 + 255) / 256), dim3(256), 0, stream,
                       noise, first_w, first_b, xA);
    hipLaunchKernelGGL(wfrag_kernel, dim3((30 * 3 * 2 * 8 * 64 + 255) / 256), dim3(256), 0, stream,
                       blk_conv_w, wfh, wfl);
    hipLaunchKernelGGL(w2frag_kernel, dim3((30 * 2 * 8 * 64 + 255) / 256), dim3(256), 0, stream,
                       blk_skip_w, blk_out_w, w2h, w2l);

    for (int i = 0; i < 30; ++i) {
        int dd = 1 << (i % 10);
        const unsigned short* xi = (i & 1) ? xB : xA;
        unsigned short* xo       = (i & 1) ? xA : xB;
        hipLaunchKernelGGL(block_kernel, dim3(T_LEN / 128, B_N), dim3(256), 0, stream,
                           xi, xo, skip,
                           g + (size_t)i * 4 * 128 * T_MEL, filt,
                           wfh + (size_t)i * 24576, wfl + (size_t)i * 24576,
                           blk_conv_b + (size_t)i * 128,
                           w2h + (size_t)i * 8192, w2l + (size_t)i * 8192,
                           blk_skip_b + (size_t)i * 64,
                           blk_out_b + (size_t)i * 64,
                           dd, i == 0 ? 1 : 0);
    }

    hipLaunchKernelGGL(final_kernel, dim3((B_N * T_LEN + 255) / 256), dim3(256), 0, stream,
                       skip, last1_w, last1_b, last2_w, last2_b, out);
}

// Round 12
// 3227.696 us; speedup vs baseline: 1.2410x; 1.2410x over previous
//
#include <hip/hip_runtime.h>
#include <math.h>

#define T_LEN 76800
#define T_MEL 300
#define B_N 4

typedef __attribute__((ext_vector_type(8))) short bf16x8;
typedef __attribute__((ext_vector_type(4))) float f32x4;
typedef __attribute__((ext_vector_type(4))) unsigned short u16x4;

__device__ inline unsigned short f2bf(float x) {
    unsigned u = __float_as_uint(x);
    u += 0x7fffu + ((u >> 16) & 1u);
    return (unsigned short)(u >> 16);
}
__device__ inline float bf2f(unsigned short h) {
    return __uint_as_float(((unsigned)h) << 16);
}

// ---------------- prep kernels ----------------

// cu0 transposed: cu0[(b*T_MEL + m)*80 + o]
__global__ void cu0_kernel(const float* __restrict__ c, const float* __restrict__ up_in_w,
                           float* __restrict__ cu0) {
    int idx = blockIdx.x * 256 + threadIdx.x;
    if (idx >= B_N * T_MEL * 80) return;
    int o = idx % 80; int rest = idx / 80; int m = rest % T_MEL; int b = rest / T_MEL;
    const float* crow = c + (size_t)(b * 80) * T_MEL;
    const float* wrow = up_in_w + o * 80;
    float acc = 0.f;
    for (int i = 0; i < 80; ++i) acc = fmaf(wrow[i], crow[(size_t)i * T_MEL + m], acc);
    cu0[idx] = acc;
}

// composite 33-tap filter prefix sums + exact edge vectors (r1 derivation, validated)
__global__ void filt_kernel(const float* __restrict__ up_conv_w, float* __restrict__ filt) {
    if (threadIdx.x != 0 || blockIdx.x != 0) return;
    float F[33], tmp[33];
    for (int j = 0; j < 9; ++j) F[j] = up_conv_w[j];
    int len = 9;
    for (int s = 1; s < 4; ++s) {
        const float* w = up_conv_w + s * 9;
        int nl = len + 8;
        for (int j = 0; j < nl; ++j) {
            float acc = 0.f;
            for (int a = 0; a < 9; ++a) { int bi = j - a; if (bi >= 0 && bi < len) acc += w[a] * F[bi]; }
            tmp[j] = acc;
        }
        for (int j = 0; j < nl; ++j) F[j] = tmp[j];
        len = nl;
    }
    float run = 0.f;
    for (int n = 0; n < 33; ++n) { filt[n] = run; run += F[n]; }
    filt[33] = run; filt[34] = run;
    const float* w1 = up_conv_w + 0;  const float* w2 = up_conv_w + 9;
    const float* w3 = up_conv_w + 18; const float* w4 = up_conv_w + 27;
    {
        float y1[28], y2[24], y3[20];
        for (int u = 0; u < 28; ++u) { float a = 0; for (int k = 0; k < 9; ++k) { int v = u + k - 4; if (v >= 0) a += w1[k]; } y1[u] = a; }
        for (int u = 0; u < 24; ++u) { float a = 0; for (int k = 0; k < 9; ++k) { int v = u + k - 4; if (v >= 0) a += w2[k] * y1[v]; } y2[u] = a; }
        for (int u = 0; u < 20; ++u) { float a = 0; for (int k = 0; k < 9; ++k) { int v = u + k - 4; if (v >= 0) a += w3[k] * y2[v]; } y3[u] = a; }
        for (int t = 0; t < 16; ++t) { float a = 0; for (int k = 0; k < 9; ++k) { int v = t + k - 4; if (v >= 0) a += w4[k] * y3[v]; } filt[40 + t] = a; }
    }
    {
        float z1[44], z2[44], z3[44];
        for (int u = 0; u < 44; ++u) { float a = 0; for (int k = 0; k < 9; ++k) { int v = u + k - 4; if (v <= 43) a += w1[k]; } z1[u] = a; }
        for (int u = 0; u < 44; ++u) { float a = 0; for (int k = 0; k < 9; ++k) { int v = u + k - 4; if (v <= 43) a += w2[k] * z1[v < 0 ? 0 : v]; } z2[u] = a; }
        for (int u = 0; u < 44; ++u) { float a = 0; for (int k = 0; k < 9; ++k) { int v = u + k - 4; if (v <= 43) a += w3[k] * z2[v < 0 ? 0 : v]; } z3[u] = a; }
        for (int j = 0; j < 16; ++j) {
            int u = 28 + j; float a = 0;
            for (int k = 0; k < 9; ++k) { int v = u + k - 4; if (v <= 43) a += w4[k] * z3[v < 0 ? 0 : v]; }
            filt[56 + j] = a;
        }
    }
}

// g[i][b][o][m] = aux_w[i][o][:] . cu0[b][m][:]  (both rows contiguous, float4)
__global__ void g_kernel(const float* __restrict__ cu0, const float* __restrict__ aux_w,
                         float* __restrict__ g) {
    int idx = blockIdx.x * 256 + threadIdx.x;
    if (idx >= 30 * B_N * 128 * T_MEL) return;
    int m = idx % T_MEL; int rest = idx / T_MEL; int o = rest % 128; rest /= 128;
    int b = rest % B_N; int i = rest / B_N;
    const float4* wrow = (const float4*)(aux_w + ((size_t)i * 128 + o) * 80);
    const float4* crow = (const float4*)(cu0 + ((size_t)b * T_MEL + m) * 80);
    float acc = 0.f;
    #pragma unroll
    for (int k = 0; k < 20; ++k) {
        float4 w4 = wrow[k], c4 = crow[k];
        acc = fmaf(w4.x, c4.x, acc); acc = fmaf(w4.y, c4.y, acc);
        acc = fmaf(w4.z, c4.z, acc); acc = fmaf(w4.w, c4.w, acc);
    }
    g[idx] = acc;
}

// x0 in [b][t][ch] bf16 layout (single plane)
__global__ void first_kernel(const float* __restrict__ noise, const float* __restrict__ fw,
                             const float* __restrict__ fb,
                             unsigned short* __restrict__ xh) {
    int idx = blockIdx.x * 256 + threadIdx.x;
    if (idx >= B_N * T_LEN * 64) return;
    int i = idx & 63; int rest = idx >> 6; int t = rest % T_LEN; int b = rest / T_LEN;
    float v = fmaf(fw[i], noise[(size_t)b * T_LEN + t], fb[i]);
    xh[idx] = f2bf(v);
}

// conv weights -> MFMA A-fragment order, hi/lo planes.
__global__ void wfrag_kernel(const float* __restrict__ conv_w,
                             unsigned short* __restrict__ wfh, unsigned short* __restrict__ wfl) {
    int idx = blockIdx.x * 256 + threadIdx.x;
    if (idx >= 30 * 3 * 2 * 8 * 64) return;
    int l = idx & 63; int r = idx >> 6;
    int m = r & 7; r >>= 3;
    int ch = r & 1; r >>= 1;
    int tap = r % 3; int layer = r / 3;
    int o = m * 16 + (l & 15);
    int i0 = ch * 32 + (l >> 4) * 8;
    #pragma unroll
    for (int j = 0; j < 8; ++j) {
        float v = conv_w[(((size_t)layer * 128 + o) * 64 + i0 + j) * 3 + tap];
        unsigned short h = f2bf(v);
        wfh[(size_t)idx * 8 + j] = h;
        wfl[(size_t)idx * 8 + j] = f2bf(v - bf2f(h));
    }
}

// skip/out weights -> fragment order.
__global__ void w2frag_kernel(const float* __restrict__ skip_w, const float* __restrict__ out_w,
                              unsigned short* __restrict__ w2h, unsigned short* __restrict__ w2l) {
    int idx = blockIdx.x * 256 + threadIdx.x;
    if (idx >= 30 * 2 * 8 * 64) return;
    int l = idx & 63; int r = idx >> 6;
    int m = r & 7; r >>= 3;
    int ch = r & 1; int layer = r >> 1;
    int o = m * 16 + (l & 15);
    int z0 = ch * 32 + (l >> 4) * 8;
    #pragma unroll
    for (int j = 0; j < 8; ++j) {
        float v = (o < 64) ? skip_w[((size_t)layer * 64 + o) * 64 + z0 + j]
                           : out_w[((size_t)layer * 64 + (o - 64)) * 64 + z0 + j];
        unsigned short h = f2bf(v);
        w2h[(size_t)idx * 8 + j] = h;
        w2l[(size_t)idx * 8 + j] = f2bf(v - bf2f(h));
    }
}

// ---------------- main residual block (r9 body; MODE 0=first,1=mid,2=last) ----------
// MODE0: skip write-only. MODE1: full. MODE2: phase 2b + x epilogue omitted (x_out dead).
template<int MODE>
__global__ __launch_bounds__(256, 3) void block_kernel(
    const unsigned short* __restrict__ xin, unsigned short* __restrict__ xout,
    float* __restrict__ skip,   // [b][t][64]
    const float* __restrict__ g, const float* __restrict__ filt,
    const unsigned short* __restrict__ wfh, const unsigned short* __restrict__ wfl,
    const float* __restrict__ conv_b,
    const unsigned short* __restrict__ w2h, const unsigned short* __restrict__ w2l,
    const float* __restrict__ skip_b, const float* __restrict__ out_b,
    int d)
{
    __shared__ unsigned short U[16384];
    __shared__ float glm[128], gll[128], glr[128], bl1[128], bl2[128];

    const int tid = threadIdx.x;
    const int wv = tid >> 6, ln = tid & 63;
    const int g4 = ln >> 4, l15 = ln & 15;
    const int b = blockIdx.y;
    const int bx = (blockIdx.x & 7) * 75 + (blockIdx.x >> 3);
    const int t0 = bx * 128;
    const int m0 = t0 >> 8;

    if (tid < 128) {
        int o = tid;
        const float* gb = g + ((size_t)b * 128 + o) * T_MEL;
        int ml = m0 > 0 ? m0 - 1 : 0;
        int mr = m0 < 299 ? m0 + 1 : 299;
        glm[o] = gb[m0]; gll[o] = gb[ml]; glr[o] = gb[mr];
        bl1[o] = conv_b[o];
    } else {
        int o = tid - 128;
        bl2[o] = (o < 64) ? skip_b[o] : out_b[o - 64];
    }

    // prologue: stage W s=0 into buf 0
    {
        bf16x8 h0 = *(const bf16x8*)(wfh + tid * 16);
        bf16x8 h1 = *(const bf16x8*)(wfh + tid * 16 + 8);
        bf16x8 l0 = *(const bf16x8*)(wfl + tid * 16);
        bf16x8 l1 = *(const bf16x8*)(wfl + tid * 16 + 8);
        *(bf16x8*)&U[tid * 16] = h0;        *(bf16x8*)&U[tid * 16 + 8] = h1;
        *(bf16x8*)&U[4096 + tid * 16] = l0; *(bf16x8*)&U[4096 + tid * 16 + 8] = l1;
    }
    __syncthreads();

    // per-ntile aux interpolation coefficients (exact)
    float am[2], al[2], ar[2];
    const float K = filt[34];
    #pragma unroll
    for (int nt = 0; nt < 2; ++nt) {
        int t = t0 + wv * 32 + nt * 16 + l15;
        int r = t & 255;
        float Am = K, Al = 0.f, Ar = 0.f;
        if (t < 16)               { Am = filt[40 + t]; }
        else if (t >= T_LEN - 16) { Am = filt[56 + (t - (T_LEN - 16))]; }
        else if (r < 16)  { float blv = filt[16 - r];     Am = K - blv; Al = blv; }
        else if (r > 239) { float bh = K - filt[272 - r]; Am = K - bh;  Ar = bh; }
        am[nt] = Am; al[nt] = Al; ar[nt] = Ar;
    }

    f32x4 acc[8][2];
    #pragma unroll
    for (int m = 0; m < 8; ++m)
        #pragma unroll
        for (int nt = 0; nt < 2; ++nt)
            #pragma unroll
            for (int r = 0; r < 4; ++r) {
                int o = m * 16 + 4 * g4 + r;
                acc[m][nt][r] = bl1[o] + am[nt] * glm[o] + al[nt] * gll[o] + ar[nt] * glr[o];
            }

    bf16x8 zfrag;
    #pragma unroll
    for (int j = 0; j < 8; ++j) zfrag[j] = 0;

    const size_t xbase = (size_t)b * T_LEN * 64;

    // ---- phase 1: 6 stages (tap,ch), W from LDS (dbuf), x (bf16) from global ----
    #pragma unroll
    for (int s = 0; s < 6; ++s) {
        const int cur = s & 1;
        if (s < 5) {
            const size_t gb_ = (size_t)(s + 1) * 4096 + tid * 16;
            bf16x8 h0 = *(const bf16x8*)(wfh + gb_);
            bf16x8 h1 = *(const bf16x8*)(wfh + gb_ + 8);
            bf16x8 l0 = *(const bf16x8*)(wfl + gb_);
            bf16x8 l1 = *(const bf16x8*)(wfl + gb_ + 8);
            unsigned short* dst = U + (cur ^ 1) * 8192;
            *(bf16x8*)&dst[tid * 16] = h0;        *(bf16x8*)&dst[tid * 16 + 8] = h1;
            *(bf16x8*)&dst[4096 + tid * 16] = l0; *(bf16x8*)&dst[4096 + tid * 16 + 8] = l1;
        }
        const int tap = s >> 1, ch = s & 1;
        const int shift = (tap - 1) * d;
        bf16x8 bx[2];
        #pragma unroll
        for (int nt = 0; nt < 2; ++nt) {
            int te = t0 + wv * 32 + nt * 16 + l15 + shift;
            if ((unsigned)te < (unsigned)T_LEN) {
                size_t a = xbase + (size_t)te * 64 + ch * 32 + g4 * 8;
                bx[nt] = *(const bf16x8*)(xin + a);
            } else {
                bx[nt] = zfrag;
            }
        }
        const unsigned short* Wh = U + cur * 8192;
        #pragma unroll
        for (int m = 0; m < 8; ++m) {
            const bf16x8 ah  = *(const bf16x8*)&Wh[(m * 64 + ln) * 8];
            const bf16x8 alo = *(const bf16x8*)&Wh[4096 + (m * 64 + ln) * 8];
            #pragma unroll
            for (int nt = 0; nt < 2; ++nt) {
                acc[m][nt] = __builtin_amdgcn_mfma_f32_16x16x32_bf16(ah,  bx[nt], acc[m][nt], 0, 0, 0);
                acc[m][nt] = __builtin_amdgcn_mfma_f32_16x16x32_bf16(alo, bx[nt], acc[m][nt], 0, 0, 0);
            }
        }
        __syncthreads();
    }

    // ---- gate -> FULL z (split) -> LDS, XOR-swizzled; acc dies here ----
    #pragma unroll
    for (int zm = 0; zm < 4; ++zm)
        #pragma unroll
        for (int nt = 0; nt < 2; ++nt) {
            u16x4 zh4, zl4;
            #pragma unroll
            for (int r = 0; r < 4; ++r) {
                float a_ = acc[zm][nt][r], b_ = acc[zm + 4][nt][r];
                float z = tanhf(a_) * (1.f / (1.f + expf(-b_)));
                unsigned short h = f2bf(z);
                zh4[r] = h; zl4[r] = f2bf(z - bf2f(h));
            }
            int trow = wv * 32 + nt * 16 + l15;
            int col = (zm * 16 + 4 * g4) ^ ((l15 & 7) << 3);
            *(u16x4*)&U[trow * 64 + col] = zh4;
            *(u16x4*)&U[8192 + trow * 64 + col] = zl4;
        }
    // Z rows are wave-private -> no barrier.

    // ---- phase 2: [skip(0..63); out(64..127)] = W2 * Z ----
    const int MROWS = (MODE == 2) ? 4 : 8;   // last layer: skip rows only
    f32x4 acc2[8][2];
    #pragma unroll
    for (int m = 0; m < 8; ++m)
        #pragma unroll
        for (int nt = 0; nt < 2; ++nt)
            #pragma unroll
            for (int r = 0; r < 4; ++r)
                acc2[m][nt][r] = bl2[m * 16 + 4 * g4 + r];

    #pragma unroll
    for (int chh = 0; chh < 2; ++chh) {
        bf16x8 bzh[2], bzl[2];
        #pragma unroll
        for (int nt = 0; nt < 2; ++nt) {
            int trow = wv * 32 + nt * 16 + l15;
            int chunk = (chh * 4 + g4) ^ (l15 & 7);
            bzh[nt] = *(const bf16x8*)&U[trow * 64 + chunk * 8];
            bzl[nt] = *(const bf16x8*)&U[8192 + trow * 64 + chunk * 8];
        }
        for (int m = 0; m < MROWS; ++m) {
            const bf16x8 ah  = *(const bf16x8*)(w2h + ((size_t)((chh * 8 + m) * 64 + ln)) * 8);
            const bf16x8 alo = *(const bf16x8*)(w2l + ((size_t)((chh * 8 + m) * 64 + ln)) * 8);
            #pragma unroll
            for (int nt = 0; nt < 2; ++nt) {
                acc2[m][nt] = __builtin_amdgcn_mfma_f32_16x16x32_bf16(ah,  bzh[nt], acc2[m][nt], 0, 0, 0);
                acc2[m][nt] = __builtin_amdgcn_mfma_f32_16x16x32_bf16(ah,  bzl[nt], acc2[m][nt], 0, 0, 0);
                acc2[m][nt] = __builtin_amdgcn_mfma_f32_16x16x32_bf16(alo, bzh[nt], acc2[m][nt], 0, 0, 0);
            }
        }
    }

    // ---- epilogue: skip [b][t][64] accumulate; x residual bf16 ----
    const size_t sbase = (size_t)b * T_LEN * 64;
    #pragma unroll
    for (int m = 0; m < 4; ++m)
        #pragma unroll
        for (int nt = 0; nt < 2; ++nt) {
            int t = t0 + wv * 32 + nt * 16 + l15;
            int o0 = m * 16 + 4 * g4;
            float* sp = skip + sbase + (size_t)t * 64 + o0;
            float4 v = make_float4(acc2[m][nt][0], acc2[m][nt][1], acc2[m][nt][2], acc2[m][nt][3]);
            if (MODE != 0) {
                float4 o = *(const float4*)sp;
                v.x += o.x; v.y += o.y; v.z += o.z; v.w += o.w;
            }
            *(float4*)sp = v;
        }
    if (MODE != 2) {
        #pragma unroll
        for (int m = 4; m < 8; ++m)
            #pragma unroll
            for (int nt = 0; nt < 2; ++nt) {
                int t = t0 + wv * 32 + nt * 16 + l15;
                int o0 = (m - 4) * 16 + 4 * g4;
                size_t a = xbase + (size_t)t * 64 + o0;
                u16x4 xh4 = *(const u16x4*)(xin + a);
                u16x4 oh;
                #pragma unroll
                for (int r = 0; r < 4; ++r) {
                    float xi = bf2f(xh4[r]);
                    float v = (acc2[m][nt][r] + xi) * 0.25f;
                    oh[r] = f2bf(v);
                }
                *(u16x4*)(xout + a) = oh;
            }
    }
}

// ---------------- epilogue ----------------
__global__ void final_kernel(const float* __restrict__ skip,
                             const float* __restrict__ l1w, const float* __restrict__ l1b,
                             const float* __restrict__ l2w, const float* __restrict__ l2b,
                             float* __restrict__ out) {
    int idx = blockIdx.x * 256 + threadIdx.x;
    if (idx >= B_N * T_LEN) return;
    int t = idx % T_LEN; int b = idx / T_LEN;
    const float scale = 0.18257418583505536f; // sqrt(1/30)
    float rbuf[64];
    const float* srow = skip + ((size_t)b * T_LEN + t) * 64;
    #pragma unroll
    for (int s = 0; s < 64; ++s) {
        float v = srow[s] * scale;
        rbuf[s] = v > 0.f ? v : 0.f;
    }
    float oacc = l2b[0];
    for (int cch = 0; cch < 64; ++cch) {
        float a = l1b[cch];
        const float* wrow = l1w + (size_t)cch * 64;
        #pragma unroll
        for (int s = 0; s < 64; ++s) a = fmaf(wrow[s], rbuf[s], a);
        a = a > 0.f ? a : 0.f;
        oacc = fmaf(l2w[cch], a, oacc);
    }
    out[idx] = oacc;
}

// ---------------- launch ----------------
extern "C" void kernel_launch(void* const* d_in, const int* in_sizes, int n_in,
                              void* d_out, int out_size, void* d_ws, size_t ws_size,
                              hipStream_t stream) {
    const float* c          = (const float*)d_in[0];
    const float* noise      = (const float*)d_in[1];
    const float* first_w    = (const float*)d_in[2];
    const float* first_b    = (const float*)d_in[3];
    const float* up_in_w    = (const float*)d_in[4];
    const float* up_conv_w  = (const float*)d_in[5];
    const float* blk_conv_w = (const float*)d_in[6];
    const float* blk_conv_b = (const float*)d_in[7];
    const float* blk_aux_w  = (const float*)d_in[8];
    const float* blk_out_w  = (const float*)d_in[9];
    const float* blk_out_b  = (const float*)d_in[10];
    const float* blk_skip_w = (const float*)d_in[11];
    const float* blk_skip_b = (const float*)d_in[12];
    const float* last1_w    = (const float*)d_in[13];
    const float* last1_b    = (const float*)d_in[14];
    const float* last2_w    = (const float*)d_in[15];
    const float* last2_b    = (const float*)d_in[16];
    float* out = (float*)d_out;
    float* ws  = (float*)d_ws;

    size_t off = 0;
    float* cu0  = ws + off; off += 96256;                     // [b][m][80]
    float* g    = ws + off; off += 30ull * 4 * 128 * T_MEL;   // 4,608,000
    float* filt = ws + off; off += 128;
    float* skip = ws + off; off += 4ull * 64 * T_LEN;         // [b][t][64]
    unsigned short* base16 = (unsigned short*)(ws + off);
    size_t o16 = 0;
    const size_t XPLANE = (size_t)B_N * T_LEN * 64;
    unsigned short* xA = base16 + o16; o16 += XPLANE;
    unsigned short* xB = base16 + o16; o16 += XPLANE;
    unsigned short* wfh = base16 + o16; o16 += 30ull * 24576;
    unsigned short* wfl = base16 + o16; o16 += 30ull * 24576;
    unsigned short* w2h = base16 + o16; o16 += 30ull * 8192;
    unsigned short* w2l = base16 + o16; o16 += 30ull * 8192;
    if (ws_size < off * sizeof(float) + o16 * sizeof(unsigned short)) return;

    hipLaunchKernelGGL(cu0_kernel, dim3((B_N * T_MEL * 80 + 255) / 256), dim3(256), 0, stream,
                       c, up_in_w, cu0);
    hipLaunchKernelGGL(filt_kernel, dim3(1), dim3(64), 0, stream, up_conv_w, filt);
    hipLaunchKernelGGL(g_kernel, dim3((30 * B_N * 128 * T_MEL + 255) / 256), dim3(256), 0, stream,
                       cu0, blk_aux_w, g);
    hipLaunchKernelGGL(first_kernel, dim3((B_N * T_LEN * 64 + 255) / 256), dim3(256), 0, stream,
                       noise, first_w, first_b, xA);
    hipLaunchKernelGGL(wfrag_kernel, dim3((30 * 3 * 2 * 8 * 64 + 255) / 256), dim3(256), 0, stream,
                       blk_conv_w, wfh, wfl);
    hipLaunchKernelGGL(w2frag_kernel, dim3((30 * 2 * 8 * 64 + 255) / 256), dim3(256), 0, stream,
                       blk_skip_w, blk_out_w, w2h, w2l);

    for (int i = 0; i < 30; ++i) {
        int dd = 1 << (i % 10);
        const unsigned short* xi = (i & 1) ? xB : xA;
        unsigned short* xo       = (i & 1) ? xA : xB;
        auto args_g   = g + (size_t)i * 4 * 128 * T_MEL;
        auto args_wfh = wfh + (size_t)i * 24576;
        auto args_wfl = wfl + (size_t)i * 24576;
        auto args_cb  = blk_conv_b + (size_t)i * 128;
        auto args_w2h = w2h + (size_t)i * 8192;
        auto args_w2l = w2l + (size_t)i * 8192;
        auto args_sb  = blk_skip_b + (size_t)i * 64;
        auto args_ob  = blk_out_b + (size_t)i * 64;
        if (i == 0) {
            hipLaunchKernelGGL((block_kernel<0>), dim3(T_LEN / 128, B_N), dim3(256), 0, stream,
                               xi, xo, skip, args_g, filt, args_wfh, args_wfl, args_cb,
                               args_w2h, args_w2l, args_sb, args_ob, dd);
        } else if (i == 29) {
            hipLaunchKernelGGL((block_kernel<2>), dim3(T_LEN / 128, B_N), dim3(256), 0, stream,
                               xi, xo, skip, args_g, filt, args_wfh, args_wfl, args_cb,
                               args_w2h, args_w2l, args_sb, args_ob, dd);
        } else {
            hipLaunchKernelGGL((block_kernel<1>), dim3(T_LEN / 128, B_N), dim3(256), 0, stream,
                               xi, xo, skip, args_g, filt, args_wfh, args_wfl, args_cb,
                               args_w2h, args_w2l, args_sb, args_ob, dd);
        }
    }

    hipLaunchKernelGGL(final_kernel, dim3((B_N * T_LEN + 255) / 256), dim3(256), 0, stream,
                       skip, last1_w, last1_b, last2_w, last2_b, out);
}

// Round 13
// 3142.111 us; speedup vs baseline: 1.2748x; 1.0272x over previous
//
#include <hip/hip_runtime.h>
#include <math.h>

#define T_LEN 76800
#define T_MEL 300
#define B_N 4

typedef __attribute__((ext_vector_type(8))) short bf16x8;
typedef __attribute__((ext_vector_type(4))) float f32x4;
typedef __attribute__((ext_vector_type(4))) unsigned short u16x4;

__device__ inline unsigned short f2bf(float x) {
    unsigned u = __float_as_uint(x);
    u += 0x7fffu + ((u >> 16) & 1u);
    return (unsigned short)(u >> 16);
}
__device__ inline float bf2f(unsigned short h) {
    return __uint_as_float(((unsigned)h) << 16);
}

// ---------------- prep kernels ----------------

// cu0[b][o][m] (r9 layout)
__global__ void cu0_kernel(const float* __restrict__ c, const float* __restrict__ up_in_w,
                           float* __restrict__ cu0) {
    int idx = blockIdx.x * 256 + threadIdx.x;
    if (idx >= B_N * 80 * T_MEL) return;
    int m = idx % T_MEL; int rest = idx / T_MEL; int o = rest % 80; int b = rest / 80;
    const float* crow = c + (size_t)(b * 80) * T_MEL;
    const float* wrow = up_in_w + o * 80;
    float acc = 0.f;
    for (int i = 0; i < 80; ++i) acc = fmaf(wrow[i], crow[(size_t)i * T_MEL + m], acc);
    cu0[idx] = acc;
}

// composite 33-tap filter prefix sums + exact edge vectors (r1 derivation, validated)
__global__ void filt_kernel(const float* __restrict__ up_conv_w, float* __restrict__ filt) {
    if (threadIdx.x != 0 || blockIdx.x != 0) return;
    float F[33], tmp[33];
    for (int j = 0; j < 9; ++j) F[j] = up_conv_w[j];
    int len = 9;
    for (int s = 1; s < 4; ++s) {
        const float* w = up_conv_w + s * 9;
        int nl = len + 8;
        for (int j = 0; j < nl; ++j) {
            float acc = 0.f;
            for (int a = 0; a < 9; ++a) { int bi = j - a; if (bi >= 0 && bi < len) acc += w[a] * F[bi]; }
            tmp[j] = acc;
        }
        for (int j = 0; j < nl; ++j) F[j] = tmp[j];
        len = nl;
    }
    float run = 0.f;
    for (int n = 0; n < 33; ++n) { filt[n] = run; run += F[n]; }
    filt[33] = run; filt[34] = run;
    const float* w1 = up_conv_w + 0;  const float* w2 = up_conv_w + 9;
    const float* w3 = up_conv_w + 18; const float* w4 = up_conv_w + 27;
    {
        float y1[28], y2[24], y3[20];
        for (int u = 0; u < 28; ++u) { float a = 0; for (int k = 0; k < 9; ++k) { int v = u + k - 4; if (v >= 0) a += w1[k]; } y1[u] = a; }
        for (int u = 0; u < 24; ++u) { float a = 0; for (int k = 0; k < 9; ++k) { int v = u + k - 4; if (v >= 0) a += w2[k] * y1[v]; } y2[u] = a; }
        for (int u = 0; u < 20; ++u) { float a = 0; for (int k = 0; k < 9; ++k) { int v = u + k - 4; if (v >= 0) a += w3[k] * y2[v]; } y3[u] = a; }
        for (int t = 0; t < 16; ++t) { float a = 0; for (int k = 0; k < 9; ++k) { int v = t + k - 4; if (v >= 0) a += w4[k] * y3[v]; } filt[40 + t] = a; }
    }
    {
        float z1[44], z2[44], z3[44];
        for (int u = 0; u < 44; ++u) { float a = 0; for (int k = 0; k < 9; ++k) { int v = u + k - 4; if (v <= 43) a += w1[k]; } z1[u] = a; }
        for (int u = 0; u < 44; ++u) { float a = 0; for (int k = 0; k < 9; ++k) { int v = u + k - 4; if (v <= 43) a += w2[k] * z1[v < 0 ? 0 : v]; } z2[u] = a; }
        for (int u = 0; u < 44; ++u) { float a = 0; for (int k = 0; k < 9; ++k) { int v = u + k - 4; if (v <= 43) a += w3[k] * z2[v < 0 ? 0 : v]; } z3[u] = a; }
        for (int j = 0; j < 16; ++j) {
            int u = 28 + j; float a = 0;
            for (int k = 0; k < 9; ++k) { int v = u + k - 4; if (v <= 43) a += w4[k] * z3[v < 0 ? 0 : v]; }
            filt[56 + j] = a;
        }
    }
}

// g[i][b][o][m]: coalesced over m (r9 pattern), 4 independent partial accumulators
__global__ void g_kernel(const float* __restrict__ cu0, const float* __restrict__ aux_w,
                         float* __restrict__ g) {
    int idx = blockIdx.x * 256 + threadIdx.x;
    if (idx >= 30 * B_N * 128 * T_MEL) return;
    int m = idx % T_MEL; int rest = idx / T_MEL; int o = rest % 128; rest /= 128;
    int b = rest % B_N; int i = rest / B_N;
    const float* wrow = aux_w + ((size_t)i * 128 + o) * 80;
    const float* crow = cu0 + (size_t)(b * 80) * T_MEL + m;
    float a0 = 0.f, a1 = 0.f, a2 = 0.f, a3 = 0.f;
    #pragma unroll
    for (int cc = 0; cc < 80; cc += 4) {
        a0 = fmaf(wrow[cc + 0], crow[(size_t)(cc + 0) * T_MEL], a0);
        a1 = fmaf(wrow[cc + 1], crow[(size_t)(cc + 1) * T_MEL], a1);
        a2 = fmaf(wrow[cc + 2], crow[(size_t)(cc + 2) * T_MEL], a2);
        a3 = fmaf(wrow[cc + 3], crow[(size_t)(cc + 3) * T_MEL], a3);
    }
    g[idx] = (a0 + a1) + (a2 + a3);
}

// x0 in [b][t][ch] bf16 layout (single plane)
__global__ void first_kernel(const float* __restrict__ noise, const float* __restrict__ fw,
                             const float* __restrict__ fb,
                             unsigned short* __restrict__ xh) {
    int idx = blockIdx.x * 256 + threadIdx.x;
    if (idx >= B_N * T_LEN * 64) return;
    int i = idx & 63; int rest = idx >> 6; int t = rest % T_LEN; int b = rest / T_LEN;
    float v = fmaf(fw[i], noise[(size_t)b * T_LEN + t], fb[i]);
    xh[idx] = f2bf(v);
}

// conv weights -> MFMA A-fragment order, hi/lo planes.
__global__ void wfrag_kernel(const float* __restrict__ conv_w,
                             unsigned short* __restrict__ wfh, unsigned short* __restrict__ wfl) {
    int idx = blockIdx.x * 256 + threadIdx.x;
    if (idx >= 30 * 3 * 2 * 8 * 64) return;
    int l = idx & 63; int r = idx >> 6;
    int m = r & 7; r >>= 3;
    int ch = r & 1; r >>= 1;
    int tap = r % 3; int layer = r / 3;
    int o = m * 16 + (l & 15);
    int i0 = ch * 32 + (l >> 4) * 8;
    #pragma unroll
    for (int j = 0; j < 8; ++j) {
        float v = conv_w[(((size_t)layer * 128 + o) * 64 + i0 + j) * 3 + tap];
        unsigned short h = f2bf(v);
        wfh[(size_t)idx * 8 + j] = h;
        wfl[(size_t)idx * 8 + j] = f2bf(v - bf2f(h));
    }
}

// skip/out weights -> fragment order.
__global__ void w2frag_kernel(const float* __restrict__ skip_w, const float* __restrict__ out_w,
                              unsigned short* __restrict__ w2h, unsigned short* __restrict__ w2l) {
    int idx = blockIdx.x * 256 + threadIdx.x;
    if (idx >= 30 * 2 * 8 * 64) return;
    int l = idx & 63; int r = idx >> 6;
    int m = r & 7; r >>= 3;
    int ch = r & 1; int layer = r >> 1;
    int o = m * 16 + (l & 15);
    int z0 = ch * 32 + (l >> 4) * 8;
    #pragma unroll
    for (int j = 0; j < 8; ++j) {
        float v = (o < 64) ? skip_w[((size_t)layer * 64 + o) * 64 + z0 + j]
                           : out_w[((size_t)layer * 64 + (o - 64)) * 64 + z0 + j];
        unsigned short h = f2bf(v);
        w2h[(size_t)idx * 8 + j] = h;
        w2l[(size_t)idx * 8 + j] = f2bf(v - bf2f(h));
    }
}

// ---------------- main residual block (r9 body; MODE 0=first,1=mid,2=last) ----------
// MODE0: skip write-only. MODE1: full. MODE2: out rows + x epilogue omitted (x_out dead).
template<int MODE>
__global__ __launch_bounds__(256, 3) void block_kernel(
    const unsigned short* __restrict__ xin, unsigned short* __restrict__ xout,
    float* __restrict__ skip,   // [b][t][64]
    const float* __restrict__ g, const float* __restrict__ filt,
    const unsigned short* __restrict__ wfh, const unsigned short* __restrict__ wfl,
    const float* __restrict__ conv_b,
    const unsigned short* __restrict__ w2h, const unsigned short* __restrict__ w2l,
    const float* __restrict__ skip_b, const float* __restrict__ out_b,
    int d)
{
    __shared__ unsigned short U[16384];
    __shared__ float glm[128], gll[128], glr[128], bl1[128], bl2[128];

    const int tid = threadIdx.x;
    const int wv = tid >> 6, ln = tid & 63;
    const int g4 = ln >> 4, l15 = ln & 15;
    const int b = blockIdx.y;
    const int bx = (blockIdx.x & 7) * 75 + (blockIdx.x >> 3);
    const int t0 = bx * 128;
    const int m0 = t0 >> 8;

    if (tid < 128) {
        int o = tid;
        const float* gb = g + ((size_t)b * 128 + o) * T_MEL;
        int ml = m0 > 0 ? m0 - 1 : 0;
        int mr = m0 < 299 ? m0 + 1 : 299;
        glm[o] = gb[m0]; gll[o] = gb[ml]; glr[o] = gb[mr];
        bl1[o] = conv_b[o];
    } else {
        int o = tid - 128;
        bl2[o] = (o < 64) ? skip_b[o] : out_b[o - 64];
    }

    // prologue: stage W s=0 into buf 0
    {
        bf16x8 h0 = *(const bf16x8*)(wfh + tid * 16);
        bf16x8 h1 = *(const bf16x8*)(wfh + tid * 16 + 8);
        bf16x8 l0 = *(const bf16x8*)(wfl + tid * 16);
        bf16x8 l1 = *(const bf16x8*)(wfl + tid * 16 + 8);
        *(bf16x8*)&U[tid * 16] = h0;        *(bf16x8*)&U[tid * 16 + 8] = h1;
        *(bf16x8*)&U[4096 + tid * 16] = l0; *(bf16x8*)&U[4096 + tid * 16 + 8] = l1;
    }
    __syncthreads();

    // per-ntile aux interpolation coefficients (exact)
    float am[2], al[2], ar[2];
    const float K = filt[34];
    #pragma unroll
    for (int nt = 0; nt < 2; ++nt) {
        int t = t0 + wv * 32 + nt * 16 + l15;
        int r = t & 255;
        float Am = K, Al = 0.f, Ar = 0.f;
        if (t < 16)               { Am = filt[40 + t]; }
        else if (t >= T_LEN - 16) { Am = filt[56 + (t - (T_LEN - 16))]; }
        else if (r < 16)  { float blv = filt[16 - r];     Am = K - blv; Al = blv; }
        else if (r > 239) { float bh = K - filt[272 - r]; Am = K - bh;  Ar = bh; }
        am[nt] = Am; al[nt] = Al; ar[nt] = Ar;
    }

    f32x4 acc[8][2];
    #pragma unroll
    for (int m = 0; m < 8; ++m)
        #pragma unroll
        for (int nt = 0; nt < 2; ++nt)
            #pragma unroll
            for (int r = 0; r < 4; ++r) {
                int o = m * 16 + 4 * g4 + r;
                acc[m][nt][r] = bl1[o] + am[nt] * glm[o] + al[nt] * gll[o] + ar[nt] * glr[o];
            }

    bf16x8 zfrag;
    #pragma unroll
    for (int j = 0; j < 8; ++j) zfrag[j] = 0;

    const size_t xbase = (size_t)b * T_LEN * 64;

    // ---- phase 1: 6 stages (tap,ch), W from LDS (dbuf), x (bf16) from global ----
    #pragma unroll
    for (int s = 0; s < 6; ++s) {
        const int cur = s & 1;
        if (s < 5) {
            const size_t gb_ = (size_t)(s + 1) * 4096 + tid * 16;
            bf16x8 h0 = *(const bf16x8*)(wfh + gb_);
            bf16x8 h1 = *(const bf16x8*)(wfh + gb_ + 8);
            bf16x8 l0 = *(const bf16x8*)(wfl + gb_);
            bf16x8 l1 = *(const bf16x8*)(wfl + gb_ + 8);
            unsigned short* dst = U + (cur ^ 1) * 8192;
            *(bf16x8*)&dst[tid * 16] = h0;        *(bf16x8*)&dst[tid * 16 + 8] = h1;
            *(bf16x8*)&dst[4096 + tid * 16] = l0; *(bf16x8*)&dst[4096 + tid * 16 + 8] = l1;
        }
        const int tap = s >> 1, ch = s & 1;
        const int shift = (tap - 1) * d;
        bf16x8 bx[2];
        #pragma unroll
        for (int nt = 0; nt < 2; ++nt) {
            int te = t0 + wv * 32 + nt * 16 + l15 + shift;
            if ((unsigned)te < (unsigned)T_LEN) {
                size_t a = xbase + (size_t)te * 64 + ch * 32 + g4 * 8;
                bx[nt] = *(const bf16x8*)(xin + a);
            } else {
                bx[nt] = zfrag;
            }
        }
        const unsigned short* Wh = U + cur * 8192;
        #pragma unroll
        for (int m = 0; m < 8; ++m) {
            const bf16x8 ah  = *(const bf16x8*)&Wh[(m * 64 + ln) * 8];
            const bf16x8 alo = *(const bf16x8*)&Wh[4096 + (m * 64 + ln) * 8];
            #pragma unroll
            for (int nt = 0; nt < 2; ++nt) {
                acc[m][nt] = __builtin_amdgcn_mfma_f32_16x16x32_bf16(ah,  bx[nt], acc[m][nt], 0, 0, 0);
                acc[m][nt] = __builtin_amdgcn_mfma_f32_16x16x32_bf16(alo, bx[nt], acc[m][nt], 0, 0, 0);
            }
        }
        __syncthreads();
    }

    // ---- gate -> FULL z (split) -> LDS, XOR-swizzled; acc dies here ----
    #pragma unroll
    for (int zm = 0; zm < 4; ++zm)
        #pragma unroll
        for (int nt = 0; nt < 2; ++nt) {
            u16x4 zh4, zl4;
            #pragma unroll
            for (int r = 0; r < 4; ++r) {
                float a_ = acc[zm][nt][r], b_ = acc[zm + 4][nt][r];
                float z = tanhf(a_) * (1.f / (1.f + expf(-b_)));
                unsigned short h = f2bf(z);
                zh4[r] = h; zl4[r] = f2bf(z - bf2f(h));
            }
            int trow = wv * 32 + nt * 16 + l15;
            int col = (zm * 16 + 4 * g4) ^ ((l15 & 7) << 3);
            *(u16x4*)&U[trow * 64 + col] = zh4;
            *(u16x4*)&U[8192 + trow * 64 + col] = zl4;
        }
    // Z rows are wave-private -> no barrier.

    // ---- phase 2: [skip(0..63); out(64..127)] = W2 * Z ----
    const int MROWS = (MODE == 2) ? 4 : 8;   // last layer: skip rows only
    f32x4 acc2[8][2];
    #pragma unroll
    for (int m = 0; m < 8; ++m)
        #pragma unroll
        for (int nt = 0; nt < 2; ++nt)
            #pragma unroll
            for (int r = 0; r < 4; ++r)
                acc2[m][nt][r] = bl2[m * 16 + 4 * g4 + r];

    #pragma unroll
    for (int chh = 0; chh < 2; ++chh) {
        bf16x8 bzh[2], bzl[2];
        #pragma unroll
        for (int nt = 0; nt < 2; ++nt) {
            int trow = wv * 32 + nt * 16 + l15;
            int chunk = (chh * 4 + g4) ^ (l15 & 7);
            bzh[nt] = *(const bf16x8*)&U[trow * 64 + chunk * 8];
            bzl[nt] = *(const bf16x8*)&U[8192 + trow * 64 + chunk * 8];
        }
        for (int m = 0; m < MROWS; ++m) {
            const bf16x8 ah  = *(const bf16x8*)(w2h + ((size_t)((chh * 8 + m) * 64 + ln)) * 8);
            const bf16x8 alo = *(const bf16x8*)(w2l + ((size_t)((chh * 8 + m) * 64 + ln)) * 8);
            #pragma unroll
            for (int nt = 0; nt < 2; ++nt) {
                acc2[m][nt] = __builtin_amdgcn_mfma_f32_16x16x32_bf16(ah,  bzh[nt], acc2[m][nt], 0, 0, 0);
                acc2[m][nt] = __builtin_amdgcn_mfma_f32_16x16x32_bf16(ah,  bzl[nt], acc2[m][nt], 0, 0, 0);
                acc2[m][nt] = __builtin_amdgcn_mfma_f32_16x16x32_bf16(alo, bzh[nt], acc2[m][nt], 0, 0, 0);
            }
        }
    }

    // ---- epilogue: skip [b][t][64] accumulate; x residual bf16 ----
    const size_t sbase = (size_t)b * T_LEN * 64;
    #pragma unroll
    for (int m = 0; m < 4; ++m)
        #pragma unroll
        for (int nt = 0; nt < 2; ++nt) {
            int t = t0 + wv * 32 + nt * 16 + l15;
            int o0 = m * 16 + 4 * g4;
            float* sp = skip + sbase + (size_t)t * 64 + o0;
            float4 v = make_float4(acc2[m][nt][0], acc2[m][nt][1], acc2[m][nt][2], acc2[m][nt][3]);
            if (MODE != 0) {
                float4 o = *(const float4*)sp;
                v.x += o.x; v.y += o.y; v.z += o.z; v.w += o.w;
            }
            *(float4*)sp = v;
        }
    if (MODE != 2) {
        #pragma unroll
        for (int m = 4; m < 8; ++m)
            #pragma unroll
            for (int nt = 0; nt < 2; ++nt) {
                int t = t0 + wv * 32 + nt * 16 + l15;
                int o0 = (m - 4) * 16 + 4 * g4;
                size_t a = xbase + (size_t)t * 64 + o0;
                u16x4 xh4 = *(const u16x4*)(xin + a);
                u16x4 oh;
                #pragma unroll
                for (int r = 0; r < 4; ++r) {
                    float xi = bf2f(xh4[r]);
                    float v = (acc2[m][nt][r] + xi) * 0.25f;
                    oh[r] = f2bf(v);
                }
                *(u16x4*)(xout + a) = oh;
            }
    }
}

// ---------------- epilogue ----------------
__global__ void final_kernel(const float* __restrict__ skip,
                             const float* __restrict__ l1w, const float* __restrict__ l1b,
                             const float* __restrict__ l2w, const float* __restrict__ l2b,
                             float* __restrict__ out) {
    int idx = blockIdx.x * 256 + threadIdx.x;
    if (idx >= B_N * T_LEN) return;
    int t = idx % T_LEN; int b = idx / T_LEN;
    const float scale = 0.18257418583505536f; // sqrt(1/30)
    float rbuf[64];
    const float* srow = skip + ((size_t)b * T_LEN + t) * 64;
    #pragma unroll
    for (int s = 0; s < 64; ++s) {
        float v = srow[s] * scale;
        rbuf[s] = v > 0.f ? v : 0.f;
    }
    float oacc = l2b[0];
    for (int cch = 0; cch < 64; ++cch) {
        float a = l1b[cch];
        const float* wrow = l1w + (size_t)cch * 64;
        #pragma unroll
        for (int s = 0; s < 64; ++s) a = fmaf(wrow[s], rbuf[s], a);
        a = a > 0.f ? a : 0.f;
        oacc = fmaf(l2w[cch], a, oacc);
    }
    out[idx] = oacc;
}

// ---------------- launch ----------------
extern "C" void kernel_launch(void* const* d_in, const int* in_sizes, int n_in,
                              void* d_out, int out_size, void* d_ws, size_t ws_size,
                              hipStream_t stream) {
    const float* c          = (const float*)d_in[0];
    const float* noise      = (const float*)d_in[1];
    const float* first_w    = (const float*)d_in[2];
    const float* first_b    = (const float*)d_in[3];
    const float* up_in_w    = (const float*)d_in[4];
    const float* up_conv_w  = (const float*)d_in[5];
    const float* blk_conv_w = (const float*)d_in[6];
    const float* blk_conv_b = (const float*)d_in[7];
    const float* blk_aux_w  = (const float*)d_in[8];
    const float* blk_out_w  = (const float*)d_in[9];
    const float* blk_out_b  = (const float*)d_in[10];
    const float* blk_skip_w = (const float*)d_in[11];
    const float* blk_skip_b = (const float*)d_in[12];
    const float* last1_w    = (const float*)d_in[13];
    const float* last1_b    = (const float*)d_in[14];
    const float* last2_w    = (const float*)d_in[15];
    const float* last2_b    = (const float*)d_in[16];
    float* out = (float*)d_out;
    float* ws  = (float*)d_ws;

    size_t off = 0;
    float* cu0  = ws + off; off += 96256;                     // [b][o][m]
    float* g    = ws + off; off += 30ull * 4 * 128 * T_MEL;   // 4,608,000
    float* filt = ws + off; off += 128;
    float* skip = ws + off; off += 4ull * 64 * T_LEN;         // [b][t][64]
    unsigned short* base16 = (unsigned short*)(ws + off);
    size_t o16 = 0;
    const size_t XPLANE = (size_t)B_N * T_LEN * 64;
    unsigned short* xA = base16 + o16; o16 += XPLANE;
    unsigned short* xB = base16 + o16; o16 += XPLANE;
    unsigned short* wfh = base16 + o16; o16 += 30ull * 24576;
    unsigned short* wfl = base16 + o16; o16 += 30ull * 24576;
    unsigned short* w2h = base16 + o16; o16 += 30ull * 8192;
    unsigned short* w2l = base16 + o16; o16 += 30ull * 8192;
    if (ws_size < off * sizeof(float) + o16 * sizeof(unsigned short)) return;

    hipLaunchKernelGGL(cu0_kernel, dim3((B_N * 80 * T_MEL + 255) / 256), dim3(256), 0, stream,
                       c, up_in_w, cu0);
    hipLaunchKernelGGL(filt_kernel, dim3(1), dim3(64), 0, stream, up_conv_w, filt);
    hipLaunchKernelGGL(g_kernel, dim3((30 * B_N * 128 * T_MEL + 255) / 256), dim3(256), 0, stream,
                       cu0, blk_aux_w, g);
    hipLaunchKernelGGL(first_kernel, dim3((B_N * T_LEN * 64 + 255) / 256), dim3(256), 0, stream,
                       noise, first_w, first_b, xA);
    hipLaunchKernelGGL(wfrag_kernel, dim3((30 * 3 * 2 * 8 * 64 + 255) / 256), dim3(256), 0, stream,
                       blk_conv_w, wfh, wfl);
    hipLaunchKernelGGL(w2frag_kernel, dim3((30 * 2 * 8 * 64 + 255) / 256), dim3(256), 0, stream,
                       blk_skip_w, blk_out_w, w2h, w2l);

    for (int i = 0; i < 30; ++i) {
        int dd = 1 << (i % 10);
        const unsigned short* xi = (i & 1) ? xB : xA;
        unsigned short* xo       = (i & 1) ? xA : xB;
        auto args_g   = g + (size_t)i * 4 * 128 * T_MEL;
        auto args_wfh = wfh + (size_t)i * 24576;
        auto args_wfl = wfl + (size_t)i * 24576;
        auto args_cb  = blk_conv_b + (size_t)i * 128;
        auto args_w2h = w2h + (size_t)i * 8192;
        auto args_w2l = w2l + (size_t)i * 8192;
        auto args_sb  = blk_skip_b + (size_t)i * 64;
        auto args_ob  = blk_out_b + (size_t)i * 64;
        if (i == 0) {
            hipLaunchKernelGGL((block_kernel<0>), dim3(T_LEN / 128, B_N), dim3(256), 0, stream,
                               xi, xo, skip, args_g, filt, args_wfh, args_wfl, args_cb,
                               args_w2h, args_w2l, args_sb, args_ob, dd);
        } else if (i == 29) {
            hipLaunchKernelGGL((block_kernel<2>), dim3(T_LEN / 128, B_N), dim3(256), 0, stream,
                               xi, xo, skip, args_g, filt, args_wfh, args_wfl, args_cb,
                               args_w2h, args_w2l, args_sb, args_ob, dd);
        } else {
            hipLaunchKernelGGL((block_kernel<1>), dim3(T_LEN / 128, B_N), dim3(256), 0, stream,
                               xi, xo, skip, args_g, filt, args_wfh, args_wfl, args_cb,
                               args_w2h, args_w2l, args_sb, args_ob, dd);
        }
    }

    hipLaunchKernelGGL(final_kernel, dim3((B_N * T_LEN + 255) / 256), dim3(256), 0, stream,
                       skip, last1_w, last1_b, last2_w, last2_b, out);
}

// Round 14
// 2925.895 us; speedup vs baseline: 1.3690x; 1.0739x over previous
//
#include <hip/hip_runtime.h>
#include <math.h>

#define T_LEN 76800
#define T_MEL 300
#define B_N 4

typedef __attribute__((ext_vector_type(8))) short bf16x8;
typedef __attribute__((ext_vector_type(4))) float f32x4;
typedef __attribute__((ext_vector_type(4))) unsigned short u16x4;
typedef __attribute__((ext_vector_type(4))) _Float16 f16x4;

__device__ inline unsigned short f2bf(float x) {
    unsigned u = __float_as_uint(x);
    u += 0x7fffu + ((u >> 16) & 1u);
    return (unsigned short)(u >> 16);
}
__device__ inline float bf2f(unsigned short h) {
    return __uint_as_float(((unsigned)h) << 16);
}

// ---------------- prep kernels ----------------

// cu0[b][o][m] (r9 layout)
__global__ void cu0_kernel(const float* __restrict__ c, const float* __restrict__ up_in_w,
                           float* __restrict__ cu0) {
    int idx = blockIdx.x * 256 + threadIdx.x;
    if (idx >= B_N * 80 * T_MEL) return;
    int m = idx % T_MEL; int rest = idx / T_MEL; int o = rest % 80; int b = rest / 80;
    const float* crow = c + (size_t)(b * 80) * T_MEL;
    const float* wrow = up_in_w + o * 80;
    float acc = 0.f;
    for (int i = 0; i < 80; ++i) acc = fmaf(wrow[i], crow[(size_t)i * T_MEL + m], acc);
    cu0[idx] = acc;
}

// composite 33-tap filter prefix sums + exact edge vectors (r1 derivation, validated)
__global__ void filt_kernel(const float* __restrict__ up_conv_w, float* __restrict__ filt) {
    if (threadIdx.x != 0 || blockIdx.x != 0) return;
    float F[33], tmp[33];
    for (int j = 0; j < 9; ++j) F[j] = up_conv_w[j];
    int len = 9;
    for (int s = 1; s < 4; ++s) {
        const float* w = up_conv_w + s * 9;
        int nl = len + 8;
        for (int j = 0; j < nl; ++j) {
            float acc = 0.f;
            for (int a = 0; a < 9; ++a) { int bi = j - a; if (bi >= 0 && bi < len) acc += w[a] * F[bi]; }
            tmp[j] = acc;
        }
        for (int j = 0; j < nl; ++j) F[j] = tmp[j];
        len = nl;
    }
    float run = 0.f;
    for (int n = 0; n < 33; ++n) { filt[n] = run; run += F[n]; }
    filt[33] = run; filt[34] = run;
    const float* w1 = up_conv_w + 0;  const float* w2 = up_conv_w + 9;
    const float* w3 = up_conv_w + 18; const float* w4 = up_conv_w + 27;
    {
        float y1[28], y2[24], y3[20];
        for (int u = 0; u < 28; ++u) { float a = 0; for (int k = 0; k < 9; ++k) { int v = u + k - 4; if (v >= 0) a += w1[k]; } y1[u] = a; }
        for (int u = 0; u < 24; ++u) { float a = 0; for (int k = 0; k < 9; ++k) { int v = u + k - 4; if (v >= 0) a += w2[k] * y1[v]; } y2[u] = a; }
        for (int u = 0; u < 20; ++u) { float a = 0; for (int k = 0; k < 9; ++k) { int v = u + k - 4; if (v >= 0) a += w3[k] * y2[v]; } y3[u] = a; }
        for (int t = 0; t < 16; ++t) { float a = 0; for (int k = 0; k < 9; ++k) { int v = t + k - 4; if (v >= 0) a += w4[k] * y3[v]; } filt[40 + t] = a; }
    }
    {
        float z1[44], z2[44], z3[44];
        for (int u = 0; u < 44; ++u) { float a = 0; for (int k = 0; k < 9; ++k) { int v = u + k - 4; if (v <= 43) a += w1[k]; } z1[u] = a; }
        for (int u = 0; u < 44; ++u) { float a = 0; for (int k = 0; k < 9; ++k) { int v = u + k - 4; if (v <= 43) a += w2[k] * z1[v < 0 ? 0 : v]; } z2[u] = a; }
        for (int u = 0; u < 44; ++u) { float a = 0; for (int k = 0; k < 9; ++k) { int v = u + k - 4; if (v <= 43) a += w3[k] * z2[v < 0 ? 0 : v]; } z3[u] = a; }
        for (int j = 0; j < 16; ++j) {
            int u = 28 + j; float a = 0;
            for (int k = 0; k < 9; ++k) { int v = u + k - 4; if (v <= 43) a += w4[k] * z3[v < 0 ? 0 : v]; }
            filt[56 + j] = a;
        }
    }
}

// g[i][b][o][m]: coalesced over m, 4 independent partial accumulators
__global__ void g_kernel(const float* __restrict__ cu0, const float* __restrict__ aux_w,
                         float* __restrict__ g) {
    int idx = blockIdx.x * 256 + threadIdx.x;
    if (idx >= 30 * B_N * 128 * T_MEL) return;
    int m = idx % T_MEL; int rest = idx / T_MEL; int o = rest % 128; rest /= 128;
    int b = rest % B_N; int i = rest / B_N;
    const float* wrow = aux_w + ((size_t)i * 128 + o) * 80;
    const float* crow = cu0 + (size_t)(b * 80) * T_MEL + m;
    float a0 = 0.f, a1 = 0.f, a2 = 0.f, a3 = 0.f;
    #pragma unroll
    for (int cc = 0; cc < 80; cc += 4) {
        a0 = fmaf(wrow[cc + 0], crow[(size_t)(cc + 0) * T_MEL], a0);
        a1 = fmaf(wrow[cc + 1], crow[(size_t)(cc + 1) * T_MEL], a1);
        a2 = fmaf(wrow[cc + 2], crow[(size_t)(cc + 2) * T_MEL], a2);
        a3 = fmaf(wrow[cc + 3], crow[(size_t)(cc + 3) * T_MEL], a3);
    }
    g[idx] = (a0 + a1) + (a2 + a3);
}

// x0 in [b][t][ch] bf16 layout (single plane)
__global__ void first_kernel(const float* __restrict__ noise, const float* __restrict__ fw,
                             const float* __restrict__ fb,
                             unsigned short* __restrict__ xh) {
    int idx = blockIdx.x * 256 + threadIdx.x;
    if (idx >= B_N * T_LEN * 64) return;
    int i = idx & 63; int rest = idx >> 6; int t = rest % T_LEN; int b = rest / T_LEN;
    float v = fmaf(fw[i], noise[(size_t)b * T_LEN + t], fb[i]);
    xh[idx] = f2bf(v);
}

// conv weights -> MFMA A-fragment order, hi/lo planes.
__global__ void wfrag_kernel(const float* __restrict__ conv_w,
                             unsigned short* __restrict__ wfh, unsigned short* __restrict__ wfl) {
    int idx = blockIdx.x * 256 + threadIdx.x;
    if (idx >= 30 * 3 * 2 * 8 * 64) return;
    int l = idx & 63; int r = idx >> 6;
    int m = r & 7; r >>= 3;
    int ch = r & 1; r >>= 1;
    int tap = r % 3; int layer = r / 3;
    int o = m * 16 + (l & 15);
    int i0 = ch * 32 + (l >> 4) * 8;
    #pragma unroll
    for (int j = 0; j < 8; ++j) {
        float v = conv_w[(((size_t)layer * 128 + o) * 64 + i0 + j) * 3 + tap];
        unsigned short h = f2bf(v);
        wfh[(size_t)idx * 8 + j] = h;
        wfl[(size_t)idx * 8 + j] = f2bf(v - bf2f(h));
    }
}

// skip/out weights -> fragment order.
__global__ void w2frag_kernel(const float* __restrict__ skip_w, const float* __restrict__ out_w,
                              unsigned short* __restrict__ w2h, unsigned short* __restrict__ w2l) {
    int idx = blockIdx.x * 256 + threadIdx.x;
    if (idx >= 30 * 2 * 8 * 64) return;
    int l = idx & 63; int r = idx >> 6;
    int m = r & 7; r >>= 3;
    int ch = r & 1; int layer = r >> 1;
    int o = m * 16 + (l & 15);
    int z0 = ch * 32 + (l >> 4) * 8;
    #pragma unroll
    for (int j = 0; j < 8; ++j) {
        float v = (o < 64) ? skip_w[((size_t)layer * 64 + o) * 64 + z0 + j]
                           : out_w[((size_t)layer * 64 + (o - 64)) * 64 + z0 + j];
        unsigned short h = f2bf(v);
        w2h[(size_t)idx * 8 + j] = h;
        w2l[(size_t)idx * 8 + j] = f2bf(v - bf2f(h));
    }
}

// ---------------- main residual block (r9 body; MODE 0=first,1=mid,2=last; fp16 skip) --
template<int MODE>
__global__ __launch_bounds__(256, 3) void block_kernel(
    const unsigned short* __restrict__ xin, unsigned short* __restrict__ xout,
    _Float16* __restrict__ skip,   // [b][t][64] fp16
    const float* __restrict__ g, const float* __restrict__ filt,
    const unsigned short* __restrict__ wfh, const unsigned short* __restrict__ wfl,
    const float* __restrict__ conv_b,
    const unsigned short* __restrict__ w2h, const unsigned short* __restrict__ w2l,
    const float* __restrict__ skip_b, const float* __restrict__ out_b,
    int d)
{
    __shared__ unsigned short U[16384];
    __shared__ float glm[128], gll[128], glr[128], bl1[128], bl2[128];

    const int tid = threadIdx.x;
    const int wv = tid >> 6, ln = tid & 63;
    const int g4 = ln >> 4, l15 = ln & 15;
    const int b = blockIdx.y;
    const int bx = (blockIdx.x & 7) * 75 + (blockIdx.x >> 3);
    const int t0 = bx * 128;
    const int m0 = t0 >> 8;

    if (tid < 128) {
        int o = tid;
        const float* gb = g + ((size_t)b * 128 + o) * T_MEL;
        int ml = m0 > 0 ? m0 - 1 : 0;
        int mr = m0 < 299 ? m0 + 1 : 299;
        glm[o] = gb[m0]; gll[o] = gb[ml]; glr[o] = gb[mr];
        bl1[o] = conv_b[o];
    } else {
        int o = tid - 128;
        bl2[o] = (o < 64) ? skip_b[o] : out_b[o - 64];
    }

    // prologue: stage W s=0 into buf 0
    {
        bf16x8 h0 = *(const bf16x8*)(wfh + tid * 16);
        bf16x8 h1 = *(const bf16x8*)(wfh + tid * 16 + 8);
        bf16x8 l0 = *(const bf16x8*)(wfl + tid * 16);
        bf16x8 l1 = *(const bf16x8*)(wfl + tid * 16 + 8);
        *(bf16x8*)&U[tid * 16] = h0;        *(bf16x8*)&U[tid * 16 + 8] = h1;
        *(bf16x8*)&U[4096 + tid * 16] = l0; *(bf16x8*)&U[4096 + tid * 16 + 8] = l1;
    }
    __syncthreads();

    // per-ntile aux interpolation coefficients (exact)
    float am[2], al[2], ar[2];
    const float K = filt[34];
    #pragma unroll
    for (int nt = 0; nt < 2; ++nt) {
        int t = t0 + wv * 32 + nt * 16 + l15;
        int r = t & 255;
        float Am = K, Al = 0.f, Ar = 0.f;
        if (t < 16)               { Am = filt[40 + t]; }
        else if (t >= T_LEN - 16) { Am = filt[56 + (t - (T_LEN - 16))]; }
        else if (r < 16)  { float blv = filt[16 - r];     Am = K - blv; Al = blv; }
        else if (r > 239) { float bh = K - filt[272 - r]; Am = K - bh;  Ar = bh; }
        am[nt] = Am; al[nt] = Al; ar[nt] = Ar;
    }

    f32x4 acc[8][2];
    #pragma unroll
    for (int m = 0; m < 8; ++m)
        #pragma unroll
        for (int nt = 0; nt < 2; ++nt)
            #pragma unroll
            for (int r = 0; r < 4; ++r) {
                int o = m * 16 + 4 * g4 + r;
                acc[m][nt][r] = bl1[o] + am[nt] * glm[o] + al[nt] * gll[o] + ar[nt] * glr[o];
            }

    bf16x8 zfrag;
    #pragma unroll
    for (int j = 0; j < 8; ++j) zfrag[j] = 0;

    const size_t xbase = (size_t)b * T_LEN * 64;

    // ---- phase 1: 6 stages (tap,ch), W from LDS (dbuf), x (bf16) from global ----
    #pragma unroll
    for (int s = 0; s < 6; ++s) {
        const int cur = s & 1;
        if (s < 5) {
            const size_t gb_ = (size_t)(s + 1) * 4096 + tid * 16;
            bf16x8 h0 = *(const bf16x8*)(wfh + gb_);
            bf16x8 h1 = *(const bf16x8*)(wfh + gb_ + 8);
            bf16x8 l0 = *(const bf16x8*)(wfl + gb_);
            bf16x8 l1 = *(const bf16x8*)(wfl + gb_ + 8);
            unsigned short* dst = U + (cur ^ 1) * 8192;
            *(bf16x8*)&dst[tid * 16] = h0;        *(bf16x8*)&dst[tid * 16 + 8] = h1;
            *(bf16x8*)&dst[4096 + tid * 16] = l0; *(bf16x8*)&dst[4096 + tid * 16 + 8] = l1;
        }
        const int tap = s >> 1, ch = s & 1;
        const int shift = (tap - 1) * d;
        bf16x8 bx[2];
        #pragma unroll
        for (int nt = 0; nt < 2; ++nt) {
            int te = t0 + wv * 32 + nt * 16 + l15 + shift;
            if ((unsigned)te < (unsigned)T_LEN) {
                size_t a = xbase + (size_t)te * 64 + ch * 32 + g4 * 8;
                bx[nt] = *(const bf16x8*)(xin + a);
            } else {
                bx[nt] = zfrag;
            }
        }
        const unsigned short* Wh = U + cur * 8192;
        #pragma unroll
        for (int m = 0; m < 8; ++m) {
            const bf16x8 ah  = *(const bf16x8*)&Wh[(m * 64 + ln) * 8];
            const bf16x8 alo = *(const bf16x8*)&Wh[4096 + (m * 64 + ln) * 8];
            #pragma unroll
            for (int nt = 0; nt < 2; ++nt) {
                acc[m][nt] = __builtin_amdgcn_mfma_f32_16x16x32_bf16(ah,  bx[nt], acc[m][nt], 0, 0, 0);
                acc[m][nt] = __builtin_amdgcn_mfma_f32_16x16x32_bf16(alo, bx[nt], acc[m][nt], 0, 0, 0);
            }
        }
        __syncthreads();
    }

    // ---- gate -> FULL z (split) -> LDS, XOR-swizzled; acc dies here ----
    #pragma unroll
    for (int zm = 0; zm < 4; ++zm)
        #pragma unroll
        for (int nt = 0; nt < 2; ++nt) {
            u16x4 zh4, zl4;
            #pragma unroll
            for (int r = 0; r < 4; ++r) {
                float a_ = acc[zm][nt][r], b_ = acc[zm + 4][nt][r];
                float z = tanhf(a_) * (1.f / (1.f + expf(-b_)));
                unsigned short h = f2bf(z);
                zh4[r] = h; zl4[r] = f2bf(z - bf2f(h));
            }
            int trow = wv * 32 + nt * 16 + l15;
            int col = (zm * 16 + 4 * g4) ^ ((l15 & 7) << 3);
            *(u16x4*)&U[trow * 64 + col] = zh4;
            *(u16x4*)&U[8192 + trow * 64 + col] = zl4;
        }
    // Z rows are wave-private -> no barrier.

    // ---- phase 2: [skip(0..63); out(64..127)] = W2 * Z ----
    constexpr int MROWS = (MODE == 2) ? 4 : 8;   // last layer: skip rows only
    f32x4 acc2[8][2];
    #pragma unroll
    for (int m = 0; m < 8; ++m)
        #pragma unroll
        for (int nt = 0; nt < 2; ++nt)
            #pragma unroll
            for (int r = 0; r < 4; ++r)
                acc2[m][nt][r] = bl2[m * 16 + 4 * g4 + r];

    #pragma unroll
    for (int chh = 0; chh < 2; ++chh) {
        bf16x8 bzh[2], bzl[2];
        #pragma unroll
        for (int nt = 0; nt < 2; ++nt) {
            int trow = wv * 32 + nt * 16 + l15;
            int chunk = (chh * 4 + g4) ^ (l15 & 7);
            bzh[nt] = *(const bf16x8*)&U[trow * 64 + chunk * 8];
            bzl[nt] = *(const bf16x8*)&U[8192 + trow * 64 + chunk * 8];
        }
        #pragma unroll
        for (int m = 0; m < MROWS; ++m) {
            const bf16x8 ah  = *(const bf16x8*)(w2h + ((size_t)((chh * 8 + m) * 64 + ln)) * 8);
            const bf16x8 alo = *(const bf16x8*)(w2l + ((size_t)((chh * 8 + m) * 64 + ln)) * 8);
            #pragma unroll
            for (int nt = 0; nt < 2; ++nt) {
                acc2[m][nt] = __builtin_amdgcn_mfma_f32_16x16x32_bf16(ah,  bzh[nt], acc2[m][nt], 0, 0, 0);
                acc2[m][nt] = __builtin_amdgcn_mfma_f32_16x16x32_bf16(ah,  bzl[nt], acc2[m][nt], 0, 0, 0);
                acc2[m][nt] = __builtin_amdgcn_mfma_f32_16x16x32_bf16(alo, bzh[nt], acc2[m][nt], 0, 0, 0);
            }
        }
    }

    // ---- epilogue: skip [b][t][64] fp16 accumulate; x residual bf16 ----
    const size_t sbase = (size_t)b * T_LEN * 64;
    #pragma unroll
    for (int m = 0; m < 4; ++m)
        #pragma unroll
        for (int nt = 0; nt < 2; ++nt) {
            int t = t0 + wv * 32 + nt * 16 + l15;
            int o0 = m * 16 + 4 * g4;
            _Float16* sp = skip + sbase + (size_t)t * 64 + o0;
            f16x4 v;
            if (MODE != 0) {
                f16x4 o = *(const f16x4*)sp;
                #pragma unroll
                for (int r = 0; r < 4; ++r)
                    v[r] = (_Float16)(acc2[m][nt][r] + (float)o[r]);
            } else {
                #pragma unroll
                for (int r = 0; r < 4; ++r)
                    v[r] = (_Float16)acc2[m][nt][r];
            }
            *(f16x4*)sp = v;
        }
    if (MODE != 2) {
        #pragma unroll
        for (int m = 4; m < 8; ++m)
            #pragma unroll
            for (int nt = 0; nt < 2; ++nt) {
                int t = t0 + wv * 32 + nt * 16 + l15;
                int o0 = (m - 4) * 16 + 4 * g4;
                size_t a = xbase + (size_t)t * 64 + o0;
                u16x4 xh4 = *(const u16x4*)(xin + a);
                u16x4 oh;
                #pragma unroll
                for (int r = 0; r < 4; ++r) {
                    float xi = bf2f(xh4[r]);
                    float v = (acc2[m][nt][r] + xi) * 0.25f;
                    oh[r] = f2bf(v);
                }
                *(u16x4*)(xout + a) = oh;
            }
    }
}

// ---------------- epilogue ----------------
__global__ void final_kernel(const _Float16* __restrict__ skip,
                             const float* __restrict__ l1w, const float* __restrict__ l1b,
                             const float* __restrict__ l2w, const float* __restrict__ l2b,
                             float* __restrict__ out) {
    int idx = blockIdx.x * 256 + threadIdx.x;
    if (idx >= B_N * T_LEN) return;
    int t = idx % T_LEN; int b = idx / T_LEN;
    const float scale = 0.18257418583505536f; // sqrt(1/30)
    float rbuf[64];
    const _Float16* srow = skip + ((size_t)b * T_LEN + t) * 64;
    #pragma unroll
    for (int s = 0; s < 64; ++s) {
        float v = (float)srow[s] * scale;
        rbuf[s] = v > 0.f ? v : 0.f;
    }
    float oacc = l2b[0];
    for (int cch = 0; cch < 64; ++cch) {
        float a = l1b[cch];
        const float* wrow = l1w + (size_t)cch * 64;
        #pragma unroll
        for (int s = 0; s < 64; ++s) a = fmaf(wrow[s], rbuf[s], a);
        a = a > 0.f ? a : 0.f;
        oacc = fmaf(l2w[cch], a, oacc);
    }
    out[idx] = oacc;
}

// ---------------- launch ----------------
extern "C" void kernel_launch(void* const* d_in, const int* in_sizes, int n_in,
                              void* d_out, int out_size, void* d_ws, size_t ws_size,
                              hipStream_t stream) {
    const float* c          = (const float*)d_in[0];
    const float* noise      = (const float*)d_in[1];
    const float* first_w    = (const float*)d_in[2];
    const float* first_b    = (const float*)d_in[3];
    const float* up_in_w    = (const float*)d_in[4];
    const float* up_conv_w  = (const float*)d_in[5];
    const float* blk_conv_w = (const float*)d_in[6];
    const float* blk_conv_b = (const float*)d_in[7];
    const float* blk_aux_w  = (const float*)d_in[8];
    const float* blk_out_w  = (const float*)d_in[9];
    const float* blk_out_b  = (const float*)d_in[10];
    const float* blk_skip_w = (const float*)d_in[11];
    const float* blk_skip_b = (const float*)d_in[12];
    const float* last1_w    = (const float*)d_in[13];
    const float* last1_b    = (const float*)d_in[14];
    const float* last2_w    = (const float*)d_in[15];
    const float* last2_b    = (const float*)d_in[16];
    float* out = (float*)d_out;
    float* ws  = (float*)d_ws;

    size_t off = 0;
    float* cu0  = ws + off; off += 96256;                     // [b][o][m]
    float* g    = ws + off; off += 30ull * 4 * 128 * T_MEL;   // 4,608,000
    float* filt = ws + off; off += 128;
    _Float16* skip = (_Float16*)(ws + off); off += 4ull * 64 * T_LEN / 2;  // fp16 [b][t][64]
    unsigned short* base16 = (unsigned short*)(ws + off);
    size_t o16 = 0;
    const size_t XPLANE = (size_t)B_N * T_LEN * 64;
    unsigned short* xA = base16 + o16; o16 += XPLANE;
    unsigned short* xB = base16 + o16; o16 += XPLANE;
    unsigned short* wfh = base16 + o16; o16 += 30ull * 24576;
    unsigned short* wfl = base16 + o16; o16 += 30ull * 24576;
    unsigned short* w2h = base16 + o16; o16 += 30ull * 8192;
    unsigned short* w2l = base16 + o16; o16 += 30ull * 8192;
    if (ws_size < off * sizeof(float) + o16 * sizeof(unsigned short)) return;

    hipLaunchKernelGGL(cu0_kernel, dim3((B_N * 80 * T_MEL + 255) / 256), dim3(256), 0, stream,
                       c, up_in_w, cu0);
    hipLaunchKernelGGL(filt_kernel, dim3(1), dim3(64), 0, stream, up_conv_w, filt);
    hipLaunchKernelGGL(g_kernel, dim3((30 * B_N * 128 * T_MEL + 255) / 256), dim3(256), 0, stream,
                       cu0, blk_aux_w, g);
    hipLaunchKernelGGL(first_kernel, dim3((B_N * T_LEN * 64 + 255) / 256), dim3(256), 0, stream,
                       noise, first_w, first_b, xA);
    hipLaunchKernelGGL(wfrag_kernel, dim3((30 * 3 * 2 * 8 * 64 + 255) / 256), dim3(256), 0, stream,
                       blk_conv_w, wfh, wfl);
    hipLaunchKernelGGL(w2frag_kernel, dim3((30 * 2 * 8 * 64 + 255) / 256), dim3(256), 0, stream,
                       blk_skip_w, blk_out_w, w2h, w2l);

    for (int i = 0; i < 30; ++i) {
        int dd = 1 << (i % 10);
        const unsigned short* xi = (i & 1) ? xB : xA;
        unsigned short* xo       = (i & 1) ? xA : xB;
        auto args_g   = g + (size_t)i * 4 * 128 * T_MEL;
        auto args_wfh = wfh + (size_t)i * 24576;
        auto args_wfl = wfl + (size_t)i * 24576;
        auto args_cb  = blk_conv_b + (size_t)i * 128;
        auto args_w2h = w2h + (size_t)i * 8192;
        auto args_w2l = w2l + (size_t)i * 8192;
        auto args_sb  = blk_skip_b + (size_t)i * 64;
        auto args_ob  = blk_out_b + (size_t)i * 64;
        if (i == 0) {
            hipLaunchKernelGGL((block_kernel<0>), dim3(T_LEN / 128, B_N), dim3(256), 0, stream,
                               xi, xo, skip, args_g, filt, args_wfh, args_wfl, args_cb,
                               args_w2h, args_w2l, args_sb, args_ob, dd);
        } else if (i == 29) {
            hipLaunchKernelGGL((block_kernel<2>), dim3(T_LEN / 128, B_N), dim3(256), 0, stream,
                               xi, xo, skip, args_g, filt, args_wfh, args_wfl, args_cb,
                               args_w2h, args_w2l, args_sb, args_ob, dd);
        } else {
            hipLaunchKernelGGL((block_kernel<1>), dim3(T_LEN / 128, B_N), dim3(256), 0, stream,
                               xi, xo, skip, args_g, filt, args_wfh, args_wfl, args_cb,
                               args_w2h, args_w2l, args_sb, args_ob, dd);
        }
    }

    hipLaunchKernelGGL(final_kernel, dim3((B_N * T_LEN + 255) / 256), dim3(256), 0, stream,
                       skip, last1_w, last1_b, last2_w, last2_b, out);
}